// Round 10
// baseline (690.134 us; speedup 1.0000x reference)
//
#include <hip/hip_runtime.h>
#include <cstdint>

// N=50000 nodes, E=1.6M edges, IN=128, H=64, OUT=32, R=8
#define HDIM 64
#define ODIM 32
#define NEG_SLOPE 0.2f
#define SCHUNK 2048

__device__ __forceinline__ unsigned f2bf_rne(float f) {
  unsigned u = __float_as_uint(f);
  return (u + 0x7FFFu + ((u >> 16) & 1u)) >> 16;  // round-to-nearest-even
}

// ---------------------------------------------------------------------------
// CSR build
// ---------------------------------------------------------------------------
__global__ __launch_bounds__(256) void count_deg_kernel(
    const int* __restrict__ dst, int* __restrict__ deg, int E) {
  int e = blockIdx.x * 256 + threadIdx.x;
  if (e < E) atomicAdd(&deg[dst[e]], 1);
}

__global__ __launch_bounds__(256) void scan_p1(const int* __restrict__ deg,
                                               int* __restrict__ bsum, int n) {
  int base = blockIdx.x * SCHUNK + threadIdx.x * 8;
  int s = 0;
#pragma unroll
  for (int j = 0; j < 8; j++) {
    int i = base + j;
    if (i < n) s += deg[i];
  }
#pragma unroll
  for (int d = 1; d < 64; d <<= 1) s += __shfl_xor(s, d, 64);
  __shared__ int ws[4];
  if ((threadIdx.x & 63) == 0) ws[threadIdx.x >> 6] = s;
  __syncthreads();
  if (threadIdx.x == 0) bsum[blockIdx.x] = ws[0] + ws[1] + ws[2] + ws[3];
}

__global__ void scan_p2(int* bsum, int nb) {
  int i = threadIdx.x;
  int v = (i < nb) ? bsum[i] : 0;
  int orig = v;
#pragma unroll
  for (int d = 1; d < 64; d <<= 1) {
    int up = __shfl_up(v, d, 64);
    if (i >= d) v += up;
  }
  if (i < nb) bsum[i] = v - orig;
}

__global__ __launch_bounds__(256) void scan_p3(const int* __restrict__ deg,
                                               const int* __restrict__ bsum,
                                               int* __restrict__ row_ptr,
                                               int n) {
  int base = blockIdx.x * SCHUNK + threadIdx.x * 8;
  int vals[8];
  int s = 0;
#pragma unroll
  for (int j = 0; j < 8; j++) {
    int i = base + j;
    vals[j] = (i < n) ? deg[i] : 0;
    s += vals[j];
  }
  int lane = threadIdx.x & 63, w = threadIdx.x >> 6;
  int v = s;
#pragma unroll
  for (int d = 1; d < 64; d <<= 1) {
    int up = __shfl_up(v, d, 64);
    if (lane >= d) v += up;
  }
  __shared__ int wsum[4];
  if (lane == 63) wsum[w] = v;
  __syncthreads();
  int woff = 0;
#pragma unroll
  for (int i = 0; i < 4; i++) woff += (i < w) ? wsum[i] : 0;
  int off = bsum[blockIdx.x] + woff + v - s;
#pragma unroll
  for (int j = 0; j < 8; j++) {
    int i = base + j;
    off += vals[j];
    if (i < n) row_ptr[i + 1] = off;
  }
  if (blockIdx.x == 0 && threadIdx.x == 0) row_ptr[0] = 0;
}

__global__ __launch_bounds__(256) void scatter_kernel(
    const int* __restrict__ src, const int* __restrict__ dst,
    const int* __restrict__ etype, const int* __restrict__ row_ptr,
    int* __restrict__ fill, int* __restrict__ edges, int E) {
  int e = blockIdx.x * 256 + threadIdx.x;
  if (e < E) {
    int d = dst[e];
    int pos = row_ptr[d] + atomicAdd(&fill[d], 1);
    edges[pos] = src[e] | (etype[e] << 16);  // N < 65536
  }
}

// ---------------------------------------------------------------------------
// Row max: maxk[row] = max_n ak[row*N + n]. One block per row.
// ---------------------------------------------------------------------------
__global__ __launch_bounds__(256) void rowmax_kernel(
    const float* __restrict__ ak, float* __restrict__ maxk, int N) {
  const float* row = ak + (size_t)blockIdx.x * N;
  float m = -1e30f;
  for (int i = threadIdx.x; i < N; i += 256) m = fmaxf(m, row[i]);
#pragma unroll
  for (int d = 1; d < 64; d <<= 1) m = fmaxf(m, __shfl_xor(m, d, 64));
  __shared__ float ws[4];
  if ((threadIdx.x & 63) == 0) ws[threadIdx.x >> 6] = m;
  __syncthreads();
  if (threadIdx.x == 0)
    maxk[blockIdx.x] = fmaxf(fmaxf(ws[0], ws[1]), fmaxf(ws[2], ws[3]));
}

// ---------------------------------------------------------------------------
// Layer-1 transform, KC=16 (~21 KB LDS). t stored as bf16.
// ---------------------------------------------------------------------------
template <int CIN>
__global__ __launch_bounds__(256) void transform_kernel(
    const float* __restrict__ f, const float* __restrict__ W,
    const float* __restrict__ q, const float* __restrict__ k,
    unsigned short* __restrict__ tb, float* __restrict__ aq,
    float* __restrict__ ak, int N) {
  constexpr int KC = 16;
  constexpr int FLD = 260;
  constexpr int WLD = 68;
  __shared__ float Fl[KC * FLD];
  __shared__ float Wl[KC * WLD];

  const int r = blockIdx.x;
  const int n0 = blockIdx.y * 256;
  const int tid = threadIdx.x;
  const int nt = tid >> 3;
  const int ot = tid & 7;
  const int on0 = ot * 8;

  float acc[8][8];
#pragma unroll
  for (int i = 0; i < 8; i++)
#pragma unroll
    for (int j = 0; j < 8; j++) acc[i][j] = 0.f;

  for (int k0 = 0; k0 < CIN; k0 += KC) {
    {
      const int kk = (tid & 3) * 4;
      const int nb = tid >> 2;  // 0..63
#pragma unroll
      for (int i = 0; i < 4; i++) {
        const int n = nb + i * 64;
        const int gn = n0 + n;
        float4 v = make_float4(0.f, 0.f, 0.f, 0.f);
        if (gn < N) v = *(const float4*)&f[(size_t)gn * CIN + k0 + kk];
        Fl[(kk + 0) * FLD + n] = v.x;
        Fl[(kk + 1) * FLD + n] = v.y;
        Fl[(kk + 2) * FLD + n] = v.z;
        Fl[(kk + 3) * FLD + n] = v.w;
      }
    }
    {
      const int oc = (tid & 15) * 4;
      const int kr = tid >> 4;  // 0..15
      float4 v = *(const float4*)&W[((size_t)r * CIN + k0 + kr) * 64 + oc];
      *(float4*)&Wl[kr * WLD + oc] = v;
    }
    __syncthreads();

#pragma unroll 4
    for (int kk = 0; kk < KC; kk++) {
      float4 fA = *(const float4*)&Fl[kk * FLD + nt * 8];
      float4 fB = *(const float4*)&Fl[kk * FLD + nt * 8 + 4];
      float4 wA = *(const float4*)&Wl[kk * WLD + on0];
      float4 wB = *(const float4*)&Wl[kk * WLD + on0 + 4];
      float fv[8] = {fA.x, fA.y, fA.z, fA.w, fB.x, fB.y, fB.z, fB.w};
      float wv[8] = {wA.x, wA.y, wA.z, wA.w, wB.x, wB.y, wB.z, wB.w};
#pragma unroll
      for (int i = 0; i < 8; i++)
#pragma unroll
        for (int j = 0; j < 8; j++) acc[i][j] = fmaf(fv[i], wv[j], acc[i][j]);
    }
    __syncthreads();
  }

  float qv[8], kv[8];
#pragma unroll
  for (int j = 0; j < 8; j++) {
    qv[j] = q[on0 + j];
    kv[j] = k[on0 + j];
  }

#pragma unroll
  for (int i = 0; i < 8; i++) {
    const int gn = n0 + nt * 8 + i;
    const bool valid = gn < N;
    if (valid) {
      unsigned pk[4];
#pragma unroll
      for (int j = 0; j < 4; j++)
        pk[j] = f2bf_rne(acc[i][2 * j]) | (f2bf_rne(acc[i][2 * j + 1]) << 16);
      *(uint4*)&tb[((size_t)r * N + gn) * 64 + on0] =
          make_uint4(pk[0], pk[1], pk[2], pk[3]);
    }
    float vq = 0.f, vk = 0.f;
#pragma unroll
    for (int j = 0; j < 8; j++) {
      vq = fmaf(acc[i][j], qv[j], vq);
      vk = fmaf(acc[i][j], kv[j], vk);
    }
#pragma unroll
    for (int d = 1; d < 8; d <<= 1) {
      vq += __shfl_xor(vq, d, 64);
      vk += __shfl_xor(vk, d, 64);
    }
    if (ot == 0 && valid) {
      aq[(size_t)r * N + gn] = vq;
      ak[(size_t)r * N + gn] = vk;
    }
  }
}

// ---------------------------------------------------------------------------
// Fused mu+lv transform, KC=16. t2 packed bf16x2 (mu|lv) via ^8 exchange.
// ---------------------------------------------------------------------------
__global__ __launch_bounds__(256) void transform2_kernel(
    const float* __restrict__ f, const float* __restrict__ Wa,
    const float* __restrict__ Wb, const float* __restrict__ qa,
    const float* __restrict__ ka, const float* __restrict__ qb,
    const float* __restrict__ kb, unsigned* __restrict__ t2p,
    float* __restrict__ aq2, float* __restrict__ ak2, int N) {
  constexpr int CIN = 64, KC = 16;
  constexpr int FLD = 132;
  constexpr int WLD = 68;
  __shared__ float Fl[KC * FLD];
  __shared__ float Wl[2][KC * WLD + 4];

  const int r = blockIdx.x;
  const int n0 = blockIdx.y * 128;
  const int tid = threadIdx.x;
  const int nt = tid >> 4;       // 0..15
  const int ot = tid & 15;       // 0..15
  const int mat = ot >> 3;       // 0=mu, 1=lv
  const int on0 = (ot & 7) * 8;  // 0..56

  float acc[8][8];
#pragma unroll
  for (int i = 0; i < 8; i++)
#pragma unroll
    for (int j = 0; j < 8; j++) acc[i][j] = 0.f;

  for (int k0 = 0; k0 < CIN; k0 += KC) {
    {
      const int kk = (tid & 3) * 4;
      const int nb = tid >> 2;  // 0..63
#pragma unroll
      for (int i = 0; i < 2; i++) {
        const int n = nb + i * 64;
        const int gn = n0 + n;
        float4 v = make_float4(0.f, 0.f, 0.f, 0.f);
        if (gn < N) v = *(const float4*)&f[(size_t)gn * CIN + k0 + kk];
        Fl[(kk + 0) * FLD + n] = v.x;
        Fl[(kk + 1) * FLD + n] = v.y;
        Fl[(kk + 2) * FLD + n] = v.z;
        Fl[(kk + 3) * FLD + n] = v.w;
      }
    }
    {
      const int oc = (tid & 15) * 4;
      const int kr = tid >> 4;  // 0..15
      float4 va = *(const float4*)&Wa[((size_t)r * CIN + k0 + kr) * 64 + oc];
      float4 vb = *(const float4*)&Wb[((size_t)r * CIN + k0 + kr) * 64 + oc];
      *(float4*)&Wl[0][kr * WLD + oc] = va;
      *(float4*)&Wl[1][kr * WLD + oc] = vb;
    }
    __syncthreads();

#pragma unroll 4
    for (int kk = 0; kk < KC; kk++) {
      float4 fA = *(const float4*)&Fl[kk * FLD + nt * 8];
      float4 fB = *(const float4*)&Fl[kk * FLD + nt * 8 + 4];
      float4 wA = *(const float4*)&Wl[mat][kk * WLD + on0];
      float4 wB = *(const float4*)&Wl[mat][kk * WLD + on0 + 4];
      float fv[8] = {fA.x, fA.y, fA.z, fA.w, fB.x, fB.y, fB.z, fB.w};
      float wv[8] = {wA.x, wA.y, wA.z, wA.w, wB.x, wB.y, wB.z, wB.w};
#pragma unroll
      for (int i = 0; i < 8; i++)
#pragma unroll
        for (int j = 0; j < 8; j++) acc[i][j] = fmaf(fv[i], wv[j], acc[i][j]);
    }
    __syncthreads();
  }

  const float* qsel = mat ? qb : qa;
  const float* ksel = mat ? kb : ka;
  float qv[8], kv[8];
#pragma unroll
  for (int j = 0; j < 8; j++) {
    qv[j] = qsel[on0 + j];
    kv[j] = ksel[on0 + j];
  }

#pragma unroll
  for (int i = 0; i < 8; i++) {
    const int gn = n0 + nt * 8 + i;
    const bool valid = gn < N;

    unsigned pk[8];
#pragma unroll
    for (int j = 0; j < 8; j++) {
      const float other = __shfl_xor(acc[i][j], 8, 64);  // all lanes active
      pk[j] = f2bf_rne(acc[i][j]) | (f2bf_rne(other) << 16);
    }
    if (mat == 0 && valid) {
      unsigned* dst = t2p + ((size_t)r * N + gn) * 64 + on0;
      *(uint4*)dst = make_uint4(pk[0], pk[1], pk[2], pk[3]);
      *(uint4*)(dst + 4) = make_uint4(pk[4], pk[5], pk[6], pk[7]);
    }

    float vq = 0.f, vk = 0.f;
#pragma unroll
    for (int j = 0; j < 8; j++) {
      vq = fmaf(acc[i][j], qv[j], vq);
      vk = fmaf(acc[i][j], kv[j], vk);
    }
#pragma unroll
    for (int d = 1; d < 8; d <<= 1) {
      vq += __shfl_xor(vq, d, 64);
      vk += __shfl_xor(vk, d, 64);
    }
    if ((ot & 7) == 0 && valid) {
      aq2[(size_t)(mat * 8 + r) * N + gn] = vq;
      ak2[(size_t)(mat * 8 + r) * N + gn] = vk;
    }
  }
}

// ---------------------------------------------------------------------------
// Layer-1 aggregate: SINGLE-PASS softmax using upper-bound shift
// m_ub = max_r leaky(aq[r,dst] + maxk[r]) >= every edge logit (leaky is
// monotone). alpha = p/sum(p) is exactly invariant to the shift, so the
// result matches the true-max version up to fp rounding. All shfl all-lanes.
// Unroll-8 batched bf16 gather.
// ---------------------------------------------------------------------------
__global__ __launch_bounds__(256) void aggregate_kernel(
    const int* __restrict__ row_ptr, const int* __restrict__ edges,
    const unsigned short* __restrict__ tb, const float* __restrict__ aq,
    const float* __restrict__ ak, const float* __restrict__ maxk,
    const float* __restrict__ bias, float* __restrict__ out, int N) {
  const int tid = threadIdx.x;
  const int w = tid >> 6, o = tid & 63;
  int wid = blockIdx.x * 4 + w;
  const bool valid = wid < N;
  if (!valid) wid = N - 1;
  const int beg = row_ptr[wid];
  const int end = valid ? row_ptr[wid + 1] : beg;
  const int deg = end - beg;

  const float aqw = aq[(size_t)(o & 7) * N + wid];

  // m_ub: lane o holds leaky(aq[o&7] + maxk[o&7]); max over each 8-group
  float v = aqw + maxk[o & 7];
  v = (v >= 0.f) ? v : NEG_SLOPE * v;
#pragma unroll
  for (int d = 1; d < 8; d <<= 1) v = fmaxf(v, __shfl_xor(v, d, 64));
  const float m = __shfl(v, 0, 64);

  // single pass: p once per edge; unroll-8 broadcast + coalesced bf16 gather
  float s = 0.f, acc = 0.f;
  for (int base = 0; base < deg; base += 64) {
    const int j = base + o;
    const int gcount = min(64, deg - base);
    const int packed = edges[beg + min(j, deg - 1)];
    const int src = packed & 0xFFFF;
    const int rr = packed >> 16;
    const int idx = rr * N + src;
    float x = __shfl(aqw, rr, 64) + ak[idx];
    x = (x >= 0.f) ? x : NEG_SLOPE * x;
    const float p = (j < deg) ? __expf(x - m) : 0.f;
    s += p;
    const int g8 = (gcount + 7) & ~7;
    for (int u = 0; u < g8; u += 8) {
      float pu[8];
      int iu[8];
#pragma unroll
      for (int q = 0; q < 8; q++) {
        pu[q] = __shfl(p, u + q, 64);
        iu[q] = __shfl(idx, u + q, 64);
      }
      unsigned short tv[8];
#pragma unroll
      for (int q = 0; q < 8; q++) tv[q] = tb[(size_t)iu[q] * 64 + o];
#pragma unroll
      for (int q = 0; q < 8; q++)
        acc = fmaf(pu[q], __uint_as_float((unsigned)tv[q] << 16), acc);
    }
  }
#pragma unroll
  for (int d = 1; d < 64; d <<= 1) s += __shfl_xor(s, d, 64);

  if (valid) {
    const float res = acc / (s + 1e-16f) + bias[o];
    out[(size_t)wid * 64 + o] = fmaxf(res, 0.f);
  }
}

// ---------------------------------------------------------------------------
// Fused mu+lv aggregate: single-pass (upper-bound shifts m0/m1), bf16x2 t2,
// unroll-8 gather, + final linears in epilogue.
// ---------------------------------------------------------------------------
__global__ __launch_bounds__(256) void aggregate2_kernel(
    const int* __restrict__ row_ptr, const int* __restrict__ edges,
    const unsigned* __restrict__ t2p, const float* __restrict__ aq2,
    const float* __restrict__ ak2, const float* __restrict__ maxk2,
    const float* __restrict__ bmu, const float* __restrict__ blv,
    const float* __restrict__ Wm, const float* __restrict__ bm,
    const float* __restrict__ Wlin, const float* __restrict__ bl,
    float* __restrict__ out_mu, float* __restrict__ out_ls, int N) {
  __shared__ float WmL[2048];
  __shared__ float WlL[2048];
  __shared__ float bL[64];
  __shared__ float hL[4][130];
  const int tid = threadIdx.x;
  for (int i = tid; i < 2048; i += 256) {
    WmL[i] = Wm[i];
    WlL[i] = Wlin[i];
  }
  if (tid < 32) {
    bL[tid] = bm[tid];
    bL[32 + tid] = bl[tid];
  }
  __syncthreads();

  const int w = tid >> 6, o = tid & 63;
  int wid = blockIdx.x * 4 + w;
  const bool valid = wid < N;
  if (!valid) wid = N - 1;
  const int beg = row_ptr[wid];
  const int end = valid ? row_ptr[wid + 1] : beg;
  const int deg = end - beg;

  const float aqw = aq2[(size_t)(o & 15) * N + wid];

  // m0/m1 upper bounds: lane o holds leaky(aq2[o&15] + maxk2[o&15]);
  // xor-reduce over each aligned 8-group; groups 0-7 -> m0, 8-15 -> m1.
  float v = aqw + maxk2[o & 15];
  v = (v >= 0.f) ? v : NEG_SLOPE * v;
#pragma unroll
  for (int d = 1; d < 8; d <<= 1) v = fmaxf(v, __shfl_xor(v, d, 64));
  const float m0 = __shfl(v, 0, 64);
  const float m1 = __shfl(v, 8, 64);

  // single pass
  float s0 = 0.f, s1 = 0.f, acc0 = 0.f, acc1 = 0.f;
  for (int base = 0; base < deg; base += 64) {
    const int j = base + o;
    const int gcount = min(64, deg - base);
    const int packed = edges[beg + min(j, deg - 1)];
    const int src = packed & 0xFFFF;
    const int rr = packed >> 16;
    const int idx = rr * N + src;
    float x0 = __shfl(aqw, rr, 64) + ak2[idx];
    float x1 = __shfl(aqw, 8 + rr, 64) + ak2[idx + 8 * N];
    x0 = (x0 >= 0.f) ? x0 : NEG_SLOPE * x0;
    x1 = (x1 >= 0.f) ? x1 : NEG_SLOPE * x1;
    const float p0 = (j < deg) ? __expf(x0 - m0) : 0.f;
    const float p1 = (j < deg) ? __expf(x1 - m1) : 0.f;
    s0 += p0;
    s1 += p1;
    const int g8 = (gcount + 7) & ~7;
    for (int u = 0; u < g8; u += 8) {
      float pu0[8], pu1[8];
      int iu[8];
#pragma unroll
      for (int q = 0; q < 8; q++) {
        pu0[q] = __shfl(p0, u + q, 64);
        pu1[q] = __shfl(p1, u + q, 64);
        iu[q] = __shfl(idx, u + q, 64);
      }
      unsigned pk[8];
#pragma unroll
      for (int q = 0; q < 8; q++) pk[q] = t2p[(size_t)iu[q] * 64 + o];
#pragma unroll
      for (int q = 0; q < 8; q++) {
        acc0 = fmaf(pu0[q], __uint_as_float(pk[q] << 16), acc0);
        acc1 = fmaf(pu1[q], __uint_as_float(pk[q] & 0xFFFF0000u), acc1);
      }
    }
  }
#pragma unroll
  for (int d = 1; d < 64; d <<= 1) {
    s0 += __shfl_xor(s0, d, 64);
    s1 += __shfl_xor(s1, d, 64);
  }

  const float h0 = fmaxf(acc0 / (s0 + 1e-16f) + bmu[o], 0.f);
  const float h1 = fmaxf(acc1 / (s1 + 1e-16f) + blv[o], 0.f);
  hL[w][o] = h0;
  hL[w][64 + o] = h1;
  __syncthreads();

  // lanes 0-31: mu linear; lanes 32-63: lv linear (0.5x for logstd)
  const float* hrow = &hL[w][(o >= 32) ? 64 : 0];
  const float* WL = (o >= 32) ? WlL : WmL;
  const int j = o & 31;
  float acc = 0.f;
#pragma unroll 8
  for (int c = 0; c < 64; c++) acc = fmaf(hrow[c], WL[c * 32 + j], acc);
  if (valid) {
    if (o < 32)
      out_mu[(size_t)wid * 32 + j] = acc + bL[j];
    else
      out_ls[(size_t)wid * 32 + j] = (acc + bL[32 + j]) * 0.5f;
  }
}

// ---------------------------------------------------------------------------
extern "C" void kernel_launch(void* const* d_in, const int* in_sizes, int n_in,
                              void* d_out, int out_size, void* d_ws,
                              size_t ws_size, hipStream_t stream) {
  const float* x = (const float*)d_in[0];
  const int* edge_index = (const int*)d_in[1];
  const int* edge_type = (const int*)d_in[2];
  const float* W1 = (const float*)d_in[3];
  const float* q1 = (const float*)d_in[4];
  const float* k1 = (const float*)d_in[5];
  const float* b1 = (const float*)d_in[6];
  const float* Wmu = (const float*)d_in[7];
  const float* qmu = (const float*)d_in[8];
  const float* kmu = (const float*)d_in[9];
  const float* bmu = (const float*)d_in[10];
  const float* Wlv = (const float*)d_in[11];
  const float* qlv = (const float*)d_in[12];
  const float* klv = (const float*)d_in[13];
  const float* blv = (const float*)d_in[14];
  const float* Wm = (const float*)d_in[15];
  const float* bm = (const float*)d_in[16];
  const float* Wl = (const float*)d_in[17];
  const float* bl = (const float*)d_in[18];

  const int N = in_sizes[0] / 128;         // 50000
  const int E = in_sizes[2];               // 1.6M
  const int R = in_sizes[3] / (128 * 64);  // 8

  float* out_mu = (float*)d_out;
  float* out_ls = (float*)d_out + (size_t)N * ODIM;

  char* wsp = (char*)d_ws;
  size_t off = 0;
  auto carve = [&](size_t bytes) {
    void* p = wsp + off;
    off += (bytes + 255) & ~(size_t)255;
    return p;
  };

  // t buffer: layer-1 bf16 (51.2 MB) then reused as bf16x2 t2 (102.4 MB)
  void* tbuf = carve((size_t)R * N * 64 * sizeof(unsigned));
  unsigned short* t1b = (unsigned short*)tbuf;
  unsigned* t2p = (unsigned*)tbuf;
  float* aq2 = (float*)carve((size_t)2 * R * N * sizeof(float));
  float* ak2 = (float*)carve((size_t)2 * R * N * sizeof(float));
  float* hidden = (float*)carve((size_t)N * HDIM * sizeof(float));
  float* maxk = (float*)carve(2 * R * sizeof(float));
  int* deg = (int*)carve((size_t)N * sizeof(int));
  int* fill = (int*)carve((size_t)N * sizeof(int));
  int* row_ptr = (int*)carve((size_t)(N + 1) * sizeof(int));
  int* bsum = (int*)carve(256 * sizeof(int));
  int* edges = (int*)carve((size_t)E * sizeof(int));

  const int* e_src = edge_index;
  const int* e_dst = edge_index + E;

  // ---- CSR build ----
  hipMemsetAsync(deg, 0, (size_t)N * sizeof(int), stream);
  hipMemsetAsync(fill, 0, (size_t)N * sizeof(int), stream);
  count_deg_kernel<<<(E + 255) / 256, 256, 0, stream>>>(e_dst, deg, E);
  const int nchunk = (N + SCHUNK - 1) / SCHUNK;
  scan_p1<<<nchunk, 256, 0, stream>>>(deg, bsum, N);
  scan_p2<<<1, 64, 0, stream>>>(bsum, nchunk);
  scan_p3<<<nchunk, 256, 0, stream>>>(deg, bsum, row_ptr, N);
  scatter_kernel<<<(E + 255) / 256, 256, 0, stream>>>(e_src, e_dst, edge_type,
                                                      row_ptr, fill, edges, E);

  const int tiles256 = (N + 255) / 256;
  const int agg_blocks = (N + 3) / 4;

  // ---- layer 1: IN=128 -> H=64 (bf16 t) ----
  transform_kernel<128><<<dim3(R, tiles256), 256, 0, stream>>>(
      x, W1, q1, k1, t1b, aq2, ak2, N);
  rowmax_kernel<<<R, 256, 0, stream>>>(ak2, maxk, N);
  aggregate_kernel<<<agg_blocks, 256, 0, stream>>>(
      row_ptr, edges, t1b, aq2, ak2, maxk, b1, hidden, N);

  // ---- fused conv_mu + conv_logvar (bf16x2 t2) + output linears ----
  const int tiles128 = (N + 127) / 128;
  transform2_kernel<<<dim3(R, tiles128), 256, 0, stream>>>(
      hidden, Wmu, Wlv, qmu, kmu, qlv, klv, t2p, aq2, ak2, N);
  rowmax_kernel<<<2 * R, 256, 0, stream>>>(ak2, maxk, N);
  aggregate2_kernel<<<agg_blocks, 256, 0, stream>>>(
      row_ptr, edges, t2p, aq2, ak2, maxk, bmu, blv, Wm, bm, Wl, bl, out_mu,
      out_ls, N);
}

// Round 11
// 643.002 us; speedup vs baseline: 1.0733x; 1.0733x over previous
//
#include <hip/hip_runtime.h>
#include <cstdint>

// N=50000 nodes, E=1.6M edges, IN=128, H=64, OUT=32, R=8
#define HDIM 64
#define ODIM 32
#define NEG_SLOPE 0.2f
#define SCHUNK 2048

__device__ __forceinline__ unsigned f2bf_rne(float f) {
  unsigned u = __float_as_uint(f);
  return (u + 0x7FFFu + ((u >> 16) & 1u)) >> 16;  // round-to-nearest-even
}

// monotonic float<->uint order-preserving encode (for atomicMax on floats)
__device__ __forceinline__ unsigned fenc(float f) {
  unsigned u = __float_as_uint(f);
  return (u & 0x80000000u) ? ~u : (u | 0x80000000u);
}
__device__ __forceinline__ float fdec(unsigned e) {
  unsigned u = (e & 0x80000000u) ? (e ^ 0x80000000u) : ~e;
  return __uint_as_float(u);
}

// ---------------------------------------------------------------------------
// CSR build
// ---------------------------------------------------------------------------
__global__ __launch_bounds__(256) void count_deg_kernel(
    const int* __restrict__ dst, int* __restrict__ deg, int E) {
  int e = blockIdx.x * 256 + threadIdx.x;
  if (e < E) atomicAdd(&deg[dst[e]], 1);
}

__global__ __launch_bounds__(256) void scan_p1(const int* __restrict__ deg,
                                               int* __restrict__ bsum, int n) {
  int base = blockIdx.x * SCHUNK + threadIdx.x * 8;
  int s = 0;
#pragma unroll
  for (int j = 0; j < 8; j++) {
    int i = base + j;
    if (i < n) s += deg[i];
  }
#pragma unroll
  for (int d = 1; d < 64; d <<= 1) s += __shfl_xor(s, d, 64);
  __shared__ int ws[4];
  if ((threadIdx.x & 63) == 0) ws[threadIdx.x >> 6] = s;
  __syncthreads();
  if (threadIdx.x == 0) bsum[blockIdx.x] = ws[0] + ws[1] + ws[2] + ws[3];
}

__global__ void scan_p2(int* bsum, int nb) {
  int i = threadIdx.x;
  int v = (i < nb) ? bsum[i] : 0;
  int orig = v;
#pragma unroll
  for (int d = 1; d < 64; d <<= 1) {
    int up = __shfl_up(v, d, 64);
    if (i >= d) v += up;
  }
  if (i < nb) bsum[i] = v - orig;
}

__global__ __launch_bounds__(256) void scan_p3(const int* __restrict__ deg,
                                               const int* __restrict__ bsum,
                                               int* __restrict__ row_ptr,
                                               int n) {
  int base = blockIdx.x * SCHUNK + threadIdx.x * 8;
  int vals[8];
  int s = 0;
#pragma unroll
  for (int j = 0; j < 8; j++) {
    int i = base + j;
    vals[j] = (i < n) ? deg[i] : 0;
    s += vals[j];
  }
  int lane = threadIdx.x & 63, w = threadIdx.x >> 6;
  int v = s;
#pragma unroll
  for (int d = 1; d < 64; d <<= 1) {
    int up = __shfl_up(v, d, 64);
    if (lane >= d) v += up;
  }
  __shared__ int wsum[4];
  if (lane == 63) wsum[w] = v;
  __syncthreads();
  int woff = 0;
#pragma unroll
  for (int i = 0; i < 4; i++) woff += (i < w) ? wsum[i] : 0;
  int off = bsum[blockIdx.x] + woff + v - s;
#pragma unroll
  for (int j = 0; j < 8; j++) {
    int i = base + j;
    off += vals[j];
    if (i < n) row_ptr[i + 1] = off;
  }
  if (blockIdx.x == 0 && threadIdx.x == 0) row_ptr[0] = 0;
}

__global__ __launch_bounds__(256) void scatter_kernel(
    const int* __restrict__ src, const int* __restrict__ dst,
    const int* __restrict__ etype, const int* __restrict__ row_ptr,
    int* __restrict__ fill, int* __restrict__ edges, int E) {
  int e = blockIdx.x * 256 + threadIdx.x;
  if (e < E) {
    int d = dst[e];
    int pos = row_ptr[d] + atomicAdd(&fill[d], 1);
    edges[pos] = src[e] | (etype[e] << 16);  // N < 65536
  }
}

// ---------------------------------------------------------------------------
// Parallel row max: grid (rows, 32 chunks); one atomicMax(enc) per block.
// maxk_enc must be zero-initialized (0 < enc of any real float).
// ---------------------------------------------------------------------------
__global__ __launch_bounds__(256) void rowmax_kernel(
    const float* __restrict__ ak, unsigned* __restrict__ maxk_enc, int N) {
  const int row = blockIdx.x;
  const int nchunks = gridDim.y;
  const int per = (N + nchunks - 1) / nchunks;
  const int beg = blockIdx.y * per;
  const int end = min(N, beg + per);
  const float* r = ak + (size_t)row * N;
  float m = -1e30f;
  for (int i = beg + threadIdx.x; i < end; i += 256) m = fmaxf(m, r[i]);
#pragma unroll
  for (int d = 1; d < 64; d <<= 1) m = fmaxf(m, __shfl_xor(m, d, 64));
  __shared__ float ws[4];
  if ((threadIdx.x & 63) == 0) ws[threadIdx.x >> 6] = m;
  __syncthreads();
  if (threadIdx.x == 0) {
    float bm = fmaxf(fmaxf(ws[0], ws[1]), fmaxf(ws[2], ws[3]));
    atomicMax(&maxk_enc[row], fenc(bm));
  }
}

// ---------------------------------------------------------------------------
// Layer-1 transform, KC=16 (~21 KB LDS). t stored as bf16.
// ---------------------------------------------------------------------------
template <int CIN>
__global__ __launch_bounds__(256) void transform_kernel(
    const float* __restrict__ f, const float* __restrict__ W,
    const float* __restrict__ q, const float* __restrict__ k,
    unsigned short* __restrict__ tb, float* __restrict__ aq,
    float* __restrict__ ak, int N) {
  constexpr int KC = 16;
  constexpr int FLD = 260;
  constexpr int WLD = 68;
  __shared__ float Fl[KC * FLD];
  __shared__ float Wl[KC * WLD];

  const int r = blockIdx.x;
  const int n0 = blockIdx.y * 256;
  const int tid = threadIdx.x;
  const int nt = tid >> 3;
  const int ot = tid & 7;
  const int on0 = ot * 8;

  float acc[8][8];
#pragma unroll
  for (int i = 0; i < 8; i++)
#pragma unroll
    for (int j = 0; j < 8; j++) acc[i][j] = 0.f;

  for (int k0 = 0; k0 < CIN; k0 += KC) {
    {
      const int kk = (tid & 3) * 4;
      const int nb = tid >> 2;  // 0..63
#pragma unroll
      for (int i = 0; i < 4; i++) {
        const int n = nb + i * 64;
        const int gn = n0 + n;
        float4 v = make_float4(0.f, 0.f, 0.f, 0.f);
        if (gn < N) v = *(const float4*)&f[(size_t)gn * CIN + k0 + kk];
        Fl[(kk + 0) * FLD + n] = v.x;
        Fl[(kk + 1) * FLD + n] = v.y;
        Fl[(kk + 2) * FLD + n] = v.z;
        Fl[(kk + 3) * FLD + n] = v.w;
      }
    }
    {
      const int oc = (tid & 15) * 4;
      const int kr = tid >> 4;  // 0..15
      float4 v = *(const float4*)&W[((size_t)r * CIN + k0 + kr) * 64 + oc];
      *(float4*)&Wl[kr * WLD + oc] = v;
    }
    __syncthreads();

#pragma unroll 4
    for (int kk = 0; kk < KC; kk++) {
      float4 fA = *(const float4*)&Fl[kk * FLD + nt * 8];
      float4 fB = *(const float4*)&Fl[kk * FLD + nt * 8 + 4];
      float4 wA = *(const float4*)&Wl[kk * WLD + on0];
      float4 wB = *(const float4*)&Wl[kk * WLD + on0 + 4];
      float fv[8] = {fA.x, fA.y, fA.z, fA.w, fB.x, fB.y, fB.z, fB.w};
      float wv[8] = {wA.x, wA.y, wA.z, wA.w, wB.x, wB.y, wB.z, wB.w};
#pragma unroll
      for (int i = 0; i < 8; i++)
#pragma unroll
        for (int j = 0; j < 8; j++) acc[i][j] = fmaf(fv[i], wv[j], acc[i][j]);
    }
    __syncthreads();
  }

  float qv[8], kv[8];
#pragma unroll
  for (int j = 0; j < 8; j++) {
    qv[j] = q[on0 + j];
    kv[j] = k[on0 + j];
  }

#pragma unroll
  for (int i = 0; i < 8; i++) {
    const int gn = n0 + nt * 8 + i;
    const bool valid = gn < N;
    if (valid) {
      unsigned pk[4];
#pragma unroll
      for (int j = 0; j < 4; j++)
        pk[j] = f2bf_rne(acc[i][2 * j]) | (f2bf_rne(acc[i][2 * j + 1]) << 16);
      *(uint4*)&tb[((size_t)r * N + gn) * 64 + on0] =
          make_uint4(pk[0], pk[1], pk[2], pk[3]);
    }
    float vq = 0.f, vk = 0.f;
#pragma unroll
    for (int j = 0; j < 8; j++) {
      vq = fmaf(acc[i][j], qv[j], vq);
      vk = fmaf(acc[i][j], kv[j], vk);
    }
#pragma unroll
    for (int d = 1; d < 8; d <<= 1) {
      vq += __shfl_xor(vq, d, 64);
      vk += __shfl_xor(vk, d, 64);
    }
    if (ot == 0 && valid) {
      aq[(size_t)r * N + gn] = vq;
      ak[(size_t)r * N + gn] = vk;
    }
  }
}

// ---------------------------------------------------------------------------
// Fused mu+lv transform, KC=16. t2 packed bf16x2 (mu|lv) via ^8 exchange.
// ---------------------------------------------------------------------------
__global__ __launch_bounds__(256) void transform2_kernel(
    const float* __restrict__ f, const float* __restrict__ Wa,
    const float* __restrict__ Wb, const float* __restrict__ qa,
    const float* __restrict__ ka, const float* __restrict__ qb,
    const float* __restrict__ kb, unsigned* __restrict__ t2p,
    float* __restrict__ aq2, float* __restrict__ ak2, int N) {
  constexpr int CIN = 64, KC = 16;
  constexpr int FLD = 132;
  constexpr int WLD = 68;
  __shared__ float Fl[KC * FLD];
  __shared__ float Wl[2][KC * WLD + 4];

  const int r = blockIdx.x;
  const int n0 = blockIdx.y * 128;
  const int tid = threadIdx.x;
  const int nt = tid >> 4;       // 0..15
  const int ot = tid & 15;       // 0..15
  const int mat = ot >> 3;       // 0=mu, 1=lv
  const int on0 = (ot & 7) * 8;  // 0..56

  float acc[8][8];
#pragma unroll
  for (int i = 0; i < 8; i++)
#pragma unroll
    for (int j = 0; j < 8; j++) acc[i][j] = 0.f;

  for (int k0 = 0; k0 < CIN; k0 += KC) {
    {
      const int kk = (tid & 3) * 4;
      const int nb = tid >> 2;  // 0..63
#pragma unroll
      for (int i = 0; i < 2; i++) {
        const int n = nb + i * 64;
        const int gn = n0 + n;
        float4 v = make_float4(0.f, 0.f, 0.f, 0.f);
        if (gn < N) v = *(const float4*)&f[(size_t)gn * CIN + k0 + kk];
        Fl[(kk + 0) * FLD + n] = v.x;
        Fl[(kk + 1) * FLD + n] = v.y;
        Fl[(kk + 2) * FLD + n] = v.z;
        Fl[(kk + 3) * FLD + n] = v.w;
      }
    }
    {
      const int oc = (tid & 15) * 4;
      const int kr = tid >> 4;  // 0..15
      float4 va = *(const float4*)&Wa[((size_t)r * CIN + k0 + kr) * 64 + oc];
      float4 vb = *(const float4*)&Wb[((size_t)r * CIN + k0 + kr) * 64 + oc];
      *(float4*)&Wl[0][kr * WLD + oc] = va;
      *(float4*)&Wl[1][kr * WLD + oc] = vb;
    }
    __syncthreads();

#pragma unroll 4
    for (int kk = 0; kk < KC; kk++) {
      float4 fA = *(const float4*)&Fl[kk * FLD + nt * 8];
      float4 fB = *(const float4*)&Fl[kk * FLD + nt * 8 + 4];
      float4 wA = *(const float4*)&Wl[mat][kk * WLD + on0];
      float4 wB = *(const float4*)&Wl[mat][kk * WLD + on0 + 4];
      float fv[8] = {fA.x, fA.y, fA.z, fA.w, fB.x, fB.y, fB.z, fB.w};
      float wv[8] = {wA.x, wA.y, wA.z, wA.w, wB.x, wB.y, wB.z, wB.w};
#pragma unroll
      for (int i = 0; i < 8; i++)
#pragma unroll
        for (int j = 0; j < 8; j++) acc[i][j] = fmaf(fv[i], wv[j], acc[i][j]);
    }
    __syncthreads();
  }

  const float* qsel = mat ? qb : qa;
  const float* ksel = mat ? kb : ka;
  float qv[8], kv[8];
#pragma unroll
  for (int j = 0; j < 8; j++) {
    qv[j] = qsel[on0 + j];
    kv[j] = ksel[on0 + j];
  }

#pragma unroll
  for (int i = 0; i < 8; i++) {
    const int gn = n0 + nt * 8 + i;
    const bool valid = gn < N;

    unsigned pk[8];
#pragma unroll
    for (int j = 0; j < 8; j++) {
      const float other = __shfl_xor(acc[i][j], 8, 64);  // all lanes active
      pk[j] = f2bf_rne(acc[i][j]) | (f2bf_rne(other) << 16);
    }
    if (mat == 0 && valid) {
      unsigned* dst = t2p + ((size_t)r * N + gn) * 64 + on0;
      *(uint4*)dst = make_uint4(pk[0], pk[1], pk[2], pk[3]);
      *(uint4*)(dst + 4) = make_uint4(pk[4], pk[5], pk[6], pk[7]);
    }

    float vq = 0.f, vk = 0.f;
#pragma unroll
    for (int j = 0; j < 8; j++) {
      vq = fmaf(acc[i][j], qv[j], vq);
      vk = fmaf(acc[i][j], kv[j], vk);
    }
#pragma unroll
    for (int d = 1; d < 8; d <<= 1) {
      vq += __shfl_xor(vq, d, 64);
      vk += __shfl_xor(vk, d, 64);
    }
    if ((ot & 7) == 0 && valid) {
      aq2[(size_t)(mat * 8 + r) * N + gn] = vq;
      ak2[(size_t)(mat * 8 + r) * N + gn] = vk;
    }
  }
}

// ---------------------------------------------------------------------------
// Layer-1 aggregate: single-pass softmax with upper-bound shift
// m_ub = max_r leaky(aq[r,dst] + maxk[r]) (leaky monotone => dominates all
// edge logits; alpha = p/sum p invariant to shift). All shfl all-lanes-active.
// ---------------------------------------------------------------------------
__global__ __launch_bounds__(256) void aggregate_kernel(
    const int* __restrict__ row_ptr, const int* __restrict__ edges,
    const unsigned short* __restrict__ tb, const float* __restrict__ aq,
    const float* __restrict__ ak, const unsigned* __restrict__ maxk_enc,
    const float* __restrict__ bias, float* __restrict__ out, int N) {
  const int tid = threadIdx.x;
  const int w = tid >> 6, o = tid & 63;
  int wid = blockIdx.x * 4 + w;
  const bool valid = wid < N;
  if (!valid) wid = N - 1;
  const int beg = row_ptr[wid];
  const int end = valid ? row_ptr[wid + 1] : beg;
  const int deg = end - beg;

  const float aqw = aq[(size_t)(o & 7) * N + wid];

  float v = aqw + fdec(maxk_enc[o & 7]);
  v = (v >= 0.f) ? v : NEG_SLOPE * v;
#pragma unroll
  for (int d = 1; d < 8; d <<= 1) v = fmaxf(v, __shfl_xor(v, d, 64));
  const float m = __shfl(v, 0, 64);

  float s = 0.f, acc = 0.f;
  for (int base = 0; base < deg; base += 64) {
    const int j = base + o;
    const int gcount = min(64, deg - base);
    const int packed = edges[beg + min(j, deg - 1)];
    const int src = packed & 0xFFFF;
    const int rr = packed >> 16;
    const int idx = rr * N + src;
    float x = __shfl(aqw, rr, 64) + ak[idx];
    x = (x >= 0.f) ? x : NEG_SLOPE * x;
    const float p = (j < deg) ? __expf(x - m) : 0.f;
    s += p;
    const int g8 = (gcount + 7) & ~7;
    for (int u = 0; u < g8; u += 8) {
      float pu[8];
      int iu[8];
#pragma unroll
      for (int q = 0; q < 8; q++) {
        pu[q] = __shfl(p, u + q, 64);
        iu[q] = __shfl(idx, u + q, 64);
      }
      unsigned short tv[8];
#pragma unroll
      for (int q = 0; q < 8; q++) tv[q] = tb[(size_t)iu[q] * 64 + o];
#pragma unroll
      for (int q = 0; q < 8; q++)
        acc = fmaf(pu[q], __uint_as_float((unsigned)tv[q] << 16), acc);
    }
  }
#pragma unroll
  for (int d = 1; d < 64; d <<= 1) s += __shfl_xor(s, d, 64);

  if (valid) {
    const float res = acc / (s + 1e-16f) + bias[o];
    out[(size_t)wid * 64 + o] = fmaxf(res, 0.f);
  }
}

// ---------------------------------------------------------------------------
// Fused mu+lv aggregate: single-pass, bf16x2 t2, unroll-8 gather, + linears.
// ---------------------------------------------------------------------------
__global__ __launch_bounds__(256) void aggregate2_kernel(
    const int* __restrict__ row_ptr, const int* __restrict__ edges,
    const unsigned* __restrict__ t2p, const float* __restrict__ aq2,
    const float* __restrict__ ak2, const unsigned* __restrict__ maxk2_enc,
    const float* __restrict__ bmu, const float* __restrict__ blv,
    const float* __restrict__ Wm, const float* __restrict__ bm,
    const float* __restrict__ Wlin, const float* __restrict__ bl,
    float* __restrict__ out_mu, float* __restrict__ out_ls, int N) {
  __shared__ float WmL[2048];
  __shared__ float WlL[2048];
  __shared__ float bL[64];
  __shared__ float hL[4][130];
  const int tid = threadIdx.x;
  for (int i = tid; i < 2048; i += 256) {
    WmL[i] = Wm[i];
    WlL[i] = Wlin[i];
  }
  if (tid < 32) {
    bL[tid] = bm[tid];
    bL[32 + tid] = bl[tid];
  }
  __syncthreads();

  const int w = tid >> 6, o = tid & 63;
  int wid = blockIdx.x * 4 + w;
  const bool valid = wid < N;
  if (!valid) wid = N - 1;
  const int beg = row_ptr[wid];
  const int end = valid ? row_ptr[wid + 1] : beg;
  const int deg = end - beg;

  const float aqw = aq2[(size_t)(o & 15) * N + wid];

  float v = aqw + fdec(maxk2_enc[o & 15]);
  v = (v >= 0.f) ? v : NEG_SLOPE * v;
#pragma unroll
  for (int d = 1; d < 8; d <<= 1) v = fmaxf(v, __shfl_xor(v, d, 64));
  const float m0 = __shfl(v, 0, 64);
  const float m1 = __shfl(v, 8, 64);

  float s0 = 0.f, s1 = 0.f, acc0 = 0.f, acc1 = 0.f;
  for (int base = 0; base < deg; base += 64) {
    const int j = base + o;
    const int gcount = min(64, deg - base);
    const int packed = edges[beg + min(j, deg - 1)];
    const int src = packed & 0xFFFF;
    const int rr = packed >> 16;
    const int idx = rr * N + src;
    float x0 = __shfl(aqw, rr, 64) + ak2[idx];
    float x1 = __shfl(aqw, 8 + rr, 64) + ak2[idx + 8 * N];
    x0 = (x0 >= 0.f) ? x0 : NEG_SLOPE * x0;
    x1 = (x1 >= 0.f) ? x1 : NEG_SLOPE * x1;
    const float p0 = (j < deg) ? __expf(x0 - m0) : 0.f;
    const float p1 = (j < deg) ? __expf(x1 - m1) : 0.f;
    s0 += p0;
    s1 += p1;
    const int g8 = (gcount + 7) & ~7;
    for (int u = 0; u < g8; u += 8) {
      float pu0[8], pu1[8];
      int iu[8];
#pragma unroll
      for (int q = 0; q < 8; q++) {
        pu0[q] = __shfl(p0, u + q, 64);
        pu1[q] = __shfl(p1, u + q, 64);
        iu[q] = __shfl(idx, u + q, 64);
      }
      unsigned pk[8];
#pragma unroll
      for (int q = 0; q < 8; q++) pk[q] = t2p[(size_t)iu[q] * 64 + o];
#pragma unroll
      for (int q = 0; q < 8; q++) {
        acc0 = fmaf(pu0[q], __uint_as_float(pk[q] << 16), acc0);
        acc1 = fmaf(pu1[q], __uint_as_float(pk[q] & 0xFFFF0000u), acc1);
      }
    }
  }
#pragma unroll
  for (int d = 1; d < 64; d <<= 1) {
    s0 += __shfl_xor(s0, d, 64);
    s1 += __shfl_xor(s1, d, 64);
  }

  const float h0 = fmaxf(acc0 / (s0 + 1e-16f) + bmu[o], 0.f);
  const float h1 = fmaxf(acc1 / (s1 + 1e-16f) + blv[o], 0.f);
  hL[w][o] = h0;
  hL[w][64 + o] = h1;
  __syncthreads();

  // lanes 0-31: mu linear; lanes 32-63: lv linear (0.5x for logstd)
  const float* hrow = &hL[w][(o >= 32) ? 64 : 0];
  const float* WL = (o >= 32) ? WlL : WmL;
  const int j = o & 31;
  float acc = 0.f;
#pragma unroll 8
  for (int c = 0; c < 64; c++) acc = fmaf(hrow[c], WL[c * 32 + j], acc);
  if (valid) {
    if (o < 32)
      out_mu[(size_t)wid * 32 + j] = acc + bL[j];
    else
      out_ls[(size_t)wid * 32 + j] = (acc + bL[32 + j]) * 0.5f;
  }
}

// ---------------------------------------------------------------------------
extern "C" void kernel_launch(void* const* d_in, const int* in_sizes, int n_in,
                              void* d_out, int out_size, void* d_ws,
                              size_t ws_size, hipStream_t stream) {
  const float* x = (const float*)d_in[0];
  const int* edge_index = (const int*)d_in[1];
  const int* edge_type = (const int*)d_in[2];
  const float* W1 = (const float*)d_in[3];
  const float* q1 = (const float*)d_in[4];
  const float* k1 = (const float*)d_in[5];
  const float* b1 = (const float*)d_in[6];
  const float* Wmu = (const float*)d_in[7];
  const float* qmu = (const float*)d_in[8];
  const float* kmu = (const float*)d_in[9];
  const float* bmu = (const float*)d_in[10];
  const float* Wlv = (const float*)d_in[11];
  const float* qlv = (const float*)d_in[12];
  const float* klv = (const float*)d_in[13];
  const float* blv = (const float*)d_in[14];
  const float* Wm = (const float*)d_in[15];
  const float* bm = (const float*)d_in[16];
  const float* Wl = (const float*)d_in[17];
  const float* bl = (const float*)d_in[18];

  const int N = in_sizes[0] / 128;         // 50000
  const int E = in_sizes[2];               // 1.6M
  const int R = in_sizes[3] / (128 * 64);  // 8

  float* out_mu = (float*)d_out;
  float* out_ls = (float*)d_out + (size_t)N * ODIM;

  char* wsp = (char*)d_ws;
  size_t off = 0;
  auto carve = [&](size_t bytes) {
    void* p = wsp + off;
    off += (bytes + 255) & ~(size_t)255;
    return p;
  };

  // t buffer: layer-1 bf16 (51.2 MB) then reused as bf16x2 t2 (102.4 MB)
  void* tbuf = carve((size_t)R * N * 64 * sizeof(unsigned));
  unsigned short* t1b = (unsigned short*)tbuf;
  unsigned* t2p = (unsigned*)tbuf;
  float* aq2 = (float*)carve((size_t)2 * R * N * sizeof(float));
  float* ak2 = (float*)carve((size_t)2 * R * N * sizeof(float));
  float* hidden = (float*)carve((size_t)N * HDIM * sizeof(float));
  unsigned* maxk_enc = (unsigned*)carve(2 * R * sizeof(unsigned));
  int* deg = (int*)carve((size_t)N * sizeof(int));
  int* fill = (int*)carve((size_t)N * sizeof(int));
  int* row_ptr = (int*)carve((size_t)(N + 1) * sizeof(int));
  int* bsum = (int*)carve(256 * sizeof(int));
  int* edges = (int*)carve((size_t)E * sizeof(int));

  const int* e_src = edge_index;
  const int* e_dst = edge_index + E;

  // ---- CSR build ----
  hipMemsetAsync(deg, 0, (size_t)N * sizeof(int), stream);
  hipMemsetAsync(fill, 0, (size_t)N * sizeof(int), stream);
  hipMemsetAsync(maxk_enc, 0, 2 * R * sizeof(unsigned), stream);
  count_deg_kernel<<<(E + 255) / 256, 256, 0, stream>>>(e_dst, deg, E);
  const int nchunk = (N + SCHUNK - 1) / SCHUNK;
  scan_p1<<<nchunk, 256, 0, stream>>>(deg, bsum, N);
  scan_p2<<<1, 64, 0, stream>>>(bsum, nchunk);
  scan_p3<<<nchunk, 256, 0, stream>>>(deg, bsum, row_ptr, N);
  scatter_kernel<<<(E + 255) / 256, 256, 0, stream>>>(e_src, e_dst, edge_type,
                                                      row_ptr, fill, edges, E);

  const int tiles256 = (N + 255) / 256;
  const int agg_blocks = (N + 3) / 4;

  // ---- layer 1: IN=128 -> H=64 (bf16 t) ----
  transform_kernel<128><<<dim3(R, tiles256), 256, 0, stream>>>(
      x, W1, q1, k1, t1b, aq2, ak2, N);
  rowmax_kernel<<<dim3(R, 32), 256, 0, stream>>>(ak2, maxk_enc, N);
  aggregate_kernel<<<agg_blocks, 256, 0, stream>>>(
      row_ptr, edges, t1b, aq2, ak2, maxk_enc, b1, hidden, N);

  // re-zero maxk for the 16 rows of layer 2 (async, overlaps aggregate tail)
  hipMemsetAsync(maxk_enc, 0, 2 * R * sizeof(unsigned), stream);

  // ---- fused conv_mu + conv_logvar (bf16x2 t2) + output linears ----
  const int tiles128 = (N + 127) / 128;
  transform2_kernel<<<dim3(R, tiles128), 256, 0, stream>>>(
      hidden, Wmu, Wlv, qmu, kmu, qlv, klv, t2p, aq2, ak2, N);
  rowmax_kernel<<<dim3(2 * R, 32), 256, 0, stream>>>(ak2, maxk_enc, N);
  aggregate2_kernel<<<agg_blocks, 256, 0, stream>>>(
      row_ptr, edges, t2p, aq2, ak2, maxk_enc, bmu, blv, Wm, bm, Wl, bl,
      out_mu, out_ls, N);
}

// Round 12
// 617.198 us; speedup vs baseline: 1.1182x; 1.0418x over previous
//
#include <hip/hip_runtime.h>
#include <cstdint>

// N=50000 nodes, E=1.6M edges, IN=128, H=64, OUT=32, R=8
#define HDIM 64
#define ODIM 32
#define NEG_SLOPE 0.2f
#define SCHUNK 2048

typedef __attribute__((ext_vector_type(8))) short v8s;   // 8 bf16 (4 VGPRs)
typedef __attribute__((ext_vector_type(4))) float v4f;   // MFMA accumulator

__device__ __forceinline__ unsigned f2bf_rne(float f) {
  unsigned u = __float_as_uint(f);
  return (u + 0x7FFFu + ((u >> 16) & 1u)) >> 16;  // round-to-nearest-even
}

// monotonic float<->uint order-preserving encode (for atomicMax on floats)
__device__ __forceinline__ unsigned fenc(float f) {
  unsigned u = __float_as_uint(f);
  return (u & 0x80000000u) ? ~u : (u | 0x80000000u);
}
__device__ __forceinline__ float fdec(unsigned e) {
  unsigned u = (e & 0x80000000u) ? (e ^ 0x80000000u) : ~e;
  return __uint_as_float(u);
}

// ---------------------------------------------------------------------------
// Prep: fp32 -> bf16 convert (x), and weight transpose+convert [r][k][o] ->
// [r][o][k] bf16 so MFMA B-fragments are contiguous 16B loads.
// ---------------------------------------------------------------------------
__global__ __launch_bounds__(256) void cvt_bf16_kernel(
    const float* __restrict__ in, unsigned short* __restrict__ out, int n) {
  int i = (blockIdx.x * 256 + threadIdx.x) * 4;
  if (i + 3 < n) {
    float4 v = *(const float4*)&in[i];
    ushort4 o;
    o.x = (unsigned short)f2bf_rne(v.x);
    o.y = (unsigned short)f2bf_rne(v.y);
    o.z = (unsigned short)f2bf_rne(v.z);
    o.w = (unsigned short)f2bf_rne(v.w);
    *(ushort4*)&out[i] = o;
  }
}

__global__ __launch_bounds__(256) void transpose_w_kernel(
    const float* __restrict__ W1, const float* __restrict__ Wmu,
    const float* __restrict__ Wlv, unsigned short* __restrict__ W1t,
    unsigned short* __restrict__ Wmut, unsigned short* __restrict__ Wlvt) {
  const int b = blockIdx.x;  // 0..23
  const int r = b & 7;
  const int which = b >> 3;
  const float* src;
  unsigned short* dst;
  int K;
  if (which == 0) {
    src = W1; dst = W1t; K = 128;
  } else if (which == 1) {
    src = Wmu; dst = Wmut; K = 64;
  } else {
    src = Wlv; dst = Wlvt; K = 64;
  }
  for (int idx = threadIdx.x; idx < K * 64; idx += 256) {
    const int kk = idx >> 6, o = idx & 63;
    dst[((size_t)r * 64 + o) * K + kk] =
        (unsigned short)f2bf_rne(src[((size_t)r * K + kk) * 64 + o]);
  }
}

// ---------------------------------------------------------------------------
// CSR build
// ---------------------------------------------------------------------------
__global__ __launch_bounds__(256) void count_deg_kernel(
    const int* __restrict__ dst, int* __restrict__ deg, int E) {
  int e = blockIdx.x * 256 + threadIdx.x;
  if (e < E) atomicAdd(&deg[dst[e]], 1);
}

__global__ __launch_bounds__(256) void scan_p1(const int* __restrict__ deg,
                                               int* __restrict__ bsum, int n) {
  int base = blockIdx.x * SCHUNK + threadIdx.x * 8;
  int s = 0;
#pragma unroll
  for (int j = 0; j < 8; j++) {
    int i = base + j;
    if (i < n) s += deg[i];
  }
#pragma unroll
  for (int d = 1; d < 64; d <<= 1) s += __shfl_xor(s, d, 64);
  __shared__ int ws[4];
  if ((threadIdx.x & 63) == 0) ws[threadIdx.x >> 6] = s;
  __syncthreads();
  if (threadIdx.x == 0) bsum[blockIdx.x] = ws[0] + ws[1] + ws[2] + ws[3];
}

__global__ void scan_p2(int* bsum, int nb) {
  int i = threadIdx.x;
  int v = (i < nb) ? bsum[i] : 0;
  int orig = v;
#pragma unroll
  for (int d = 1; d < 64; d <<= 1) {
    int up = __shfl_up(v, d, 64);
    if (i >= d) v += up;
  }
  if (i < nb) bsum[i] = v - orig;
}

__global__ __launch_bounds__(256) void scan_p3(const int* __restrict__ deg,
                                               const int* __restrict__ bsum,
                                               int* __restrict__ row_ptr,
                                               int n) {
  int base = blockIdx.x * SCHUNK + threadIdx.x * 8;
  int vals[8];
  int s = 0;
#pragma unroll
  for (int j = 0; j < 8; j++) {
    int i = base + j;
    vals[j] = (i < n) ? deg[i] : 0;
    s += vals[j];
  }
  int lane = threadIdx.x & 63, w = threadIdx.x >> 6;
  int v = s;
#pragma unroll
  for (int d = 1; d < 64; d <<= 1) {
    int up = __shfl_up(v, d, 64);
    if (lane >= d) v += up;
  }
  __shared__ int wsum[4];
  if (lane == 63) wsum[w] = v;
  __syncthreads();
  int woff = 0;
#pragma unroll
  for (int i = 0; i < 4; i++) woff += (i < w) ? wsum[i] : 0;
  int off = bsum[blockIdx.x] + woff + v - s;
#pragma unroll
  for (int j = 0; j < 8; j++) {
    int i = base + j;
    off += vals[j];
    if (i < n) row_ptr[i + 1] = off;
  }
  if (blockIdx.x == 0 && threadIdx.x == 0) row_ptr[0] = 0;
}

__global__ __launch_bounds__(256) void scatter_kernel(
    const int* __restrict__ src, const int* __restrict__ dst,
    const int* __restrict__ etype, const int* __restrict__ row_ptr,
    int* __restrict__ fill, int* __restrict__ edges, int E) {
  int e = blockIdx.x * 256 + threadIdx.x;
  if (e < E) {
    int d = dst[e];
    int pos = row_ptr[d] + atomicAdd(&fill[d], 1);
    edges[pos] = src[e] | (etype[e] << 16);  // N < 65536
  }
}

// ---------------------------------------------------------------------------
// Parallel row max: grid (rows, 32 chunks); one atomicMax(enc) per block.
// ---------------------------------------------------------------------------
__global__ __launch_bounds__(256) void rowmax_kernel(
    const float* __restrict__ ak, unsigned* __restrict__ maxk_enc, int N) {
  const int row = blockIdx.x;
  const int nchunks = gridDim.y;
  const int per = (N + nchunks - 1) / nchunks;
  const int beg = blockIdx.y * per;
  const int end = min(N, beg + per);
  const float* r = ak + (size_t)row * N;
  float m = -1e30f;
  for (int i = beg + threadIdx.x; i < end; i += 256) m = fmaxf(m, r[i]);
#pragma unroll
  for (int d = 1; d < 64; d <<= 1) m = fmaxf(m, __shfl_xor(m, d, 64));
  __shared__ float ws[4];
  if ((threadIdx.x & 63) == 0) ws[threadIdx.x >> 6] = m;
  __syncthreads();
  if (threadIdx.x == 0) {
    float bm = fmaxf(fmaxf(ws[0], ws[1]), fmaxf(ws[2], ws[3]));
    atomicMax(&maxk_enc[row], fenc(bm));
  }
}

// ---------------------------------------------------------------------------
// Layer-1 transform via MFMA bf16: t[r] = x @ W1[r], + fp32 aq/ak epilogue.
// Wave = 16 nodes x 64 outs; 4 col-tiles x 4 K-steps = 16 MFMAs.
// A[m=lane&15][k=quad*8+j] <- xb rows; B[n=lane&15][k=quad*8+j] <- W1t rows.
// C: col=lane&15, row=quad*4+reg. t stored via padded-LDS repack (coalesced).
// ---------------------------------------------------------------------------
__global__ __launch_bounds__(256) void transform1_mfma(
    const unsigned short* __restrict__ xb,
    const unsigned short* __restrict__ W1t, const float* __restrict__ q,
    const float* __restrict__ k, unsigned short* __restrict__ tb,
    float* __restrict__ aq, float* __restrict__ ak, int N) {
  __shared__ unsigned short st[4][16][72];  // pad 72: conflict-free + aligned
  const int r = blockIdx.x;
  const int tid = threadIdx.x;
  const int w = tid >> 6;
  const int lane = tid & 63;
  const int quad = lane >> 4;
  const int mrow = lane & 15;
  const int n0w = blockIdx.y * 64 + w * 16;

  const int gA = min(n0w + mrow, N - 1);
  const unsigned short* arow = xb + (size_t)gA * 128 + quad * 8;
  const unsigned short* wrow = W1t + ((size_t)r * 64 + mrow) * 128 + quad * 8;

  v4f acc[4];
#pragma unroll
  for (int tt = 0; tt < 4; tt++) acc[tt] = (v4f){0.f, 0.f, 0.f, 0.f};

#pragma unroll
  for (int k0 = 0; k0 < 128; k0 += 32) {
    v8s a = *(const v8s*)(arow + k0);
#pragma unroll
    for (int tt = 0; tt < 4; tt++) {
      v8s b = *(const v8s*)(wrow + (size_t)tt * 16 * 128 + k0);
      acc[tt] = __builtin_amdgcn_mfma_f32_16x16x32_bf16(a, b, acc[tt], 0, 0, 0);
    }
  }

  float qv[4], kv[4];
#pragma unroll
  for (int tt = 0; tt < 4; tt++) {
    qv[tt] = q[tt * 16 + mrow];
    kv[tt] = k[tt * 16 + mrow];
  }

#pragma unroll
  for (int i = 0; i < 4; i++) {
    float vq = 0.f, vk = 0.f;
#pragma unroll
    for (int tt = 0; tt < 4; tt++) {
      vq = fmaf(acc[tt][i], qv[tt], vq);
      vk = fmaf(acc[tt][i], kv[tt], vk);
      st[w][quad * 4 + i][tt * 16 + mrow] =
          (unsigned short)f2bf_rne(acc[tt][i]);
    }
#pragma unroll
    for (int d = 1; d < 16; d <<= 1) {  // reduce over lane bits 0-3 (quad-loc)
      vq += __shfl_xor(vq, d, 64);
      vk += __shfl_xor(vk, d, 64);
    }
    const int gn = n0w + quad * 4 + i;
    if (mrow == 0 && gn < N) {
      aq[(size_t)r * N + gn] = vq;
      ak[(size_t)r * N + gn] = vk;
    }
  }
  __syncthreads();

  // coalesced store: lane covers 16 cols of one row (2x uint4 = 32B)
  const int row = lane >> 2, cg = lane & 3;
  const int gns = n0w + row;
  if (gns < N) {
    const uint4 v0 = *(const uint4*)&st[w][row][cg * 16];
    const uint4 v1 = *(const uint4*)&st[w][row][cg * 16 + 8];
    uint4* dst = (uint4*)&tb[((size_t)r * N + gns) * 64 + cg * 16];
    dst[0] = v0;
    dst[1] = v1;
  }
}

// ---------------------------------------------------------------------------
// Fused mu+lv transform via MFMA bf16 (CIN=64): shared A-frags feed both
// weight sets; t2p packed bf16x2 (mu|lv); aq2/ak2 for both mats.
// ---------------------------------------------------------------------------
__global__ __launch_bounds__(256) void transform2_mfma(
    const unsigned short* __restrict__ hb,
    const unsigned short* __restrict__ Wmut,
    const unsigned short* __restrict__ Wlvt, const float* __restrict__ qa,
    const float* __restrict__ ka, const float* __restrict__ qb,
    const float* __restrict__ kb, unsigned* __restrict__ t2p,
    float* __restrict__ aq2, float* __restrict__ ak2, int N) {
  __shared__ unsigned st2[4][16][68];  // pad 68: 2-way max + 16B aligned rows
  const int r = blockIdx.x;
  const int tid = threadIdx.x;
  const int w = tid >> 6;
  const int lane = tid & 63;
  const int quad = lane >> 4;
  const int mrow = lane & 15;
  const int n0w = blockIdx.y * 64 + w * 16;

  const int gA = min(n0w + mrow, N - 1);
  const unsigned short* arow = hb + (size_t)gA * 64 + quad * 8;
  const size_t woff = ((size_t)r * 64 + mrow) * 64 + quad * 8;

  v4f am[4], al[4];
#pragma unroll
  for (int tt = 0; tt < 4; tt++) {
    am[tt] = (v4f){0.f, 0.f, 0.f, 0.f};
    al[tt] = (v4f){0.f, 0.f, 0.f, 0.f};
  }

#pragma unroll
  for (int k0 = 0; k0 < 64; k0 += 32) {
    v8s a = *(const v8s*)(arow + k0);
#pragma unroll
    for (int tt = 0; tt < 4; tt++) {
      v8s bm = *(const v8s*)(Wmut + woff + (size_t)tt * 16 * 64 + k0);
      v8s bl = *(const v8s*)(Wlvt + woff + (size_t)tt * 16 * 64 + k0);
      am[tt] = __builtin_amdgcn_mfma_f32_16x16x32_bf16(a, bm, am[tt], 0, 0, 0);
      al[tt] = __builtin_amdgcn_mfma_f32_16x16x32_bf16(a, bl, al[tt], 0, 0, 0);
    }
  }

  float qmv[4], kmv[4], qlv2[4], klv2[4];
#pragma unroll
  for (int tt = 0; tt < 4; tt++) {
    qmv[tt] = qa[tt * 16 + mrow];
    kmv[tt] = ka[tt * 16 + mrow];
    qlv2[tt] = qb[tt * 16 + mrow];
    klv2[tt] = kb[tt * 16 + mrow];
  }

#pragma unroll
  for (int i = 0; i < 4; i++) {
    float vqm = 0.f, vkm = 0.f, vql = 0.f, vkl = 0.f;
#pragma unroll
    for (int tt = 0; tt < 4; tt++) {
      vqm = fmaf(am[tt][i], qmv[tt], vqm);
      vkm = fmaf(am[tt][i], kmv[tt], vkm);
      vql = fmaf(al[tt][i], qlv2[tt], vql);
      vkl = fmaf(al[tt][i], klv2[tt], vkl);
      st2[w][quad * 4 + i][tt * 16 + mrow] =
          f2bf_rne(am[tt][i]) | (f2bf_rne(al[tt][i]) << 16);
    }
#pragma unroll
    for (int d = 1; d < 16; d <<= 1) {
      vqm += __shfl_xor(vqm, d, 64);
      vkm += __shfl_xor(vkm, d, 64);
      vql += __shfl_xor(vql, d, 64);
      vkl += __shfl_xor(vkl, d, 64);
    }
    const int gn = n0w + quad * 4 + i;
    if (mrow == 0 && gn < N) {
      aq2[(size_t)r * N + gn] = vqm;
      ak2[(size_t)r * N + gn] = vkm;
      aq2[(size_t)(8 + r) * N + gn] = vql;
      ak2[(size_t)(8 + r) * N + gn] = vkl;
    }
  }
  __syncthreads();

  // coalesced store: lane covers 16 uints of one row (4x uint4 = 64B)
  const int row = lane >> 2, cg = lane & 3;
  const int gns = n0w + row;
  if (gns < N) {
    unsigned* dst = &t2p[((size_t)r * N + gns) * 64 + cg * 16];
#pragma unroll
    for (int s = 0; s < 4; s++)
      *(uint4*)(dst + s * 4) = *(const uint4*)&st2[w][row][cg * 16 + s * 4];
  }
}

// ---------------------------------------------------------------------------
// Layer-1 aggregate: single-pass softmax (upper-bound shift), bf16 t gather,
// unroll-8. Writes hidden as bf16. All shfl all-lanes-active.
// ---------------------------------------------------------------------------
__global__ __launch_bounds__(256) void aggregate_kernel(
    const int* __restrict__ row_ptr, const int* __restrict__ edges,
    const unsigned short* __restrict__ tb, const float* __restrict__ aq,
    const float* __restrict__ ak, const unsigned* __restrict__ maxk_enc,
    const float* __restrict__ bias, unsigned short* __restrict__ hb, int N) {
  const int tid = threadIdx.x;
  const int w = tid >> 6, o = tid & 63;
  int wid = blockIdx.x * 4 + w;
  const bool valid = wid < N;
  if (!valid) wid = N - 1;
  const int beg = row_ptr[wid];
  const int end = valid ? row_ptr[wid + 1] : beg;
  const int deg = end - beg;

  const float aqw = aq[(size_t)(o & 7) * N + wid];

  float v = aqw + fdec(maxk_enc[o & 7]);
  v = (v >= 0.f) ? v : NEG_SLOPE * v;
#pragma unroll
  for (int d = 1; d < 8; d <<= 1) v = fmaxf(v, __shfl_xor(v, d, 64));
  const float m = __shfl(v, 0, 64);

  float s = 0.f, acc = 0.f;
  for (int base = 0; base < deg; base += 64) {
    const int j = base + o;
    const int gcount = min(64, deg - base);
    const int packed = edges[beg + min(j, deg - 1)];
    const int src = packed & 0xFFFF;
    const int rr = packed >> 16;
    const int idx = rr * N + src;
    float x = __shfl(aqw, rr, 64) + ak[idx];
    x = (x >= 0.f) ? x : NEG_SLOPE * x;
    const float p = (j < deg) ? __expf(x - m) : 0.f;
    s += p;
    const int g8 = (gcount + 7) & ~7;
    for (int u = 0; u < g8; u += 8) {
      float pu[8];
      int iu[8];
#pragma unroll
      for (int q = 0; q < 8; q++) {
        pu[q] = __shfl(p, u + q, 64);
        iu[q] = __shfl(idx, u + q, 64);
      }
      unsigned short tv[8];
#pragma unroll
      for (int q = 0; q < 8; q++) tv[q] = tb[(size_t)iu[q] * 64 + o];
#pragma unroll
      for (int q = 0; q < 8; q++)
        acc = fmaf(pu[q], __uint_as_float((unsigned)tv[q] << 16), acc);
    }
  }
#pragma unroll
  for (int d = 1; d < 64; d <<= 1) s += __shfl_xor(s, d, 64);

  if (valid) {
    const float res = acc / (s + 1e-16f) + bias[o];
    hb[(size_t)wid * 64 + o] = (unsigned short)f2bf_rne(fmaxf(res, 0.f));
  }
}

// ---------------------------------------------------------------------------
// Fused mu+lv aggregate: single-pass, bf16x2 t2, unroll-8 gather, + linears.
// ---------------------------------------------------------------------------
__global__ __launch_bounds__(256) void aggregate2_kernel(
    const int* __restrict__ row_ptr, const int* __restrict__ edges,
    const unsigned* __restrict__ t2p, const float* __restrict__ aq2,
    const float* __restrict__ ak2, const unsigned* __restrict__ maxk2_enc,
    const float* __restrict__ bmu, const float* __restrict__ blv,
    const float* __restrict__ Wm, const float* __restrict__ bm,
    const float* __restrict__ Wlin, const float* __restrict__ bl,
    float* __restrict__ out_mu, float* __restrict__ out_ls, int N) {
  __shared__ float WmL[2048];
  __shared__ float WlL[2048];
  __shared__ float bL[64];
  __shared__ float hL[4][130];
  const int tid = threadIdx.x;
  for (int i = tid; i < 2048; i += 256) {
    WmL[i] = Wm[i];
    WlL[i] = Wlin[i];
  }
  if (tid < 32) {
    bL[tid] = bm[tid];
    bL[32 + tid] = bl[tid];
  }
  __syncthreads();

  const int w = tid >> 6, o = tid & 63;
  int wid = blockIdx.x * 4 + w;
  const bool valid = wid < N;
  if (!valid) wid = N - 1;
  const int beg = row_ptr[wid];
  const int end = valid ? row_ptr[wid + 1] : beg;
  const int deg = end - beg;

  const float aqw = aq2[(size_t)(o & 15) * N + wid];

  float v = aqw + fdec(maxk2_enc[o & 15]);
  v = (v >= 0.f) ? v : NEG_SLOPE * v;
#pragma unroll
  for (int d = 1; d < 8; d <<= 1) v = fmaxf(v, __shfl_xor(v, d, 64));
  const float m0 = __shfl(v, 0, 64);
  const float m1 = __shfl(v, 8, 64);

  float s0 = 0.f, s1 = 0.f, acc0 = 0.f, acc1 = 0.f;
  for (int base = 0; base < deg; base += 64) {
    const int j = base + o;
    const int gcount = min(64, deg - base);
    const int packed = edges[beg + min(j, deg - 1)];
    const int src = packed & 0xFFFF;
    const int rr = packed >> 16;
    const int idx = rr * N + src;
    float x0 = __shfl(aqw, rr, 64) + ak2[idx];
    float x1 = __shfl(aqw, 8 + rr, 64) + ak2[idx + 8 * N];
    x0 = (x0 >= 0.f) ? x0 : NEG_SLOPE * x0;
    x1 = (x1 >= 0.f) ? x1 : NEG_SLOPE * x1;
    const float p0 = (j < deg) ? __expf(x0 - m0) : 0.f;
    const float p1 = (j < deg) ? __expf(x1 - m1) : 0.f;
    s0 += p0;
    s1 += p1;
    const int g8 = (gcount + 7) & ~7;
    for (int u = 0; u < g8; u += 8) {
      float pu0[8], pu1[8];
      int iu[8];
#pragma unroll
      for (int q = 0; q < 8; q++) {
        pu0[q] = __shfl(p0, u + q, 64);
        pu1[q] = __shfl(p1, u + q, 64);
        iu[q] = __shfl(idx, u + q, 64);
      }
      unsigned pk[8];
#pragma unroll
      for (int q = 0; q < 8; q++) pk[q] = t2p[(size_t)iu[q] * 64 + o];
#pragma unroll
      for (int q = 0; q < 8; q++) {
        acc0 = fmaf(pu0[q], __uint_as_float(pk[q] << 16), acc0);
        acc1 = fmaf(pu1[q], __uint_as_float(pk[q] & 0xFFFF0000u), acc1);
      }
    }
  }
#pragma unroll
  for (int d = 1; d < 64; d <<= 1) {
    s0 += __shfl_xor(s0, d, 64);
    s1 += __shfl_xor(s1, d, 64);
  }

  const float h0 = fmaxf(acc0 / (s0 + 1e-16f) + bmu[o], 0.f);
  const float h1 = fmaxf(acc1 / (s1 + 1e-16f) + blv[o], 0.f);
  hL[w][o] = h0;
  hL[w][64 + o] = h1;
  __syncthreads();

  // lanes 0-31: mu linear; lanes 32-63: lv linear (0.5x for logstd)
  const float* hrow = &hL[w][(o >= 32) ? 64 : 0];
  const float* WL = (o >= 32) ? WlL : WmL;
  const int j = o & 31;
  float acc = 0.f;
#pragma unroll 8
  for (int c = 0; c < 64; c++) acc = fmaf(hrow[c], WL[c * 32 + j], acc);
  if (valid) {
    if (o < 32)
      out_mu[(size_t)wid * 32 + j] = acc + bL[j];
    else
      out_ls[(size_t)wid * 32 + j] = (acc + bL[32 + j]) * 0.5f;
  }
}

// ---------------------------------------------------------------------------
extern "C" void kernel_launch(void* const* d_in, const int* in_sizes, int n_in,
                              void* d_out, int out_size, void* d_ws,
                              size_t ws_size, hipStream_t stream) {
  const float* x = (const float*)d_in[0];
  const int* edge_index = (const int*)d_in[1];
  const int* edge_type = (const int*)d_in[2];
  const float* W1 = (const float*)d_in[3];
  const float* q1 = (const float*)d_in[4];
  const float* k1 = (const float*)d_in[5];
  const float* b1 = (const float*)d_in[6];
  const float* Wmu = (const float*)d_in[7];
  const float* qmu = (const float*)d_in[8];
  const float* kmu = (const float*)d_in[9];
  const float* bmu = (const float*)d_in[10];
  const float* Wlv = (const float*)d_in[11];
  const float* qlv = (const float*)d_in[12];
  const float* klv = (const float*)d_in[13];
  const float* blv = (const float*)d_in[14];
  const float* Wm = (const float*)d_in[15];
  const float* bm = (const float*)d_in[16];
  const float* Wl = (const float*)d_in[17];
  const float* bl = (const float*)d_in[18];

  const int N = in_sizes[0] / 128;         // 50000
  const int E = in_sizes[2];               // 1.6M
  const int R = in_sizes[3] / (128 * 64);  // 8

  float* out_mu = (float*)d_out;
  float* out_ls = (float*)d_out + (size_t)N * ODIM;

  char* wsp = (char*)d_ws;
  size_t off = 0;
  auto carve = [&](size_t bytes) {
    void* p = wsp + off;
    off += (bytes + 255) & ~(size_t)255;
    return p;
  };

  // t buffer: layer-1 bf16 (51.2 MB) then reused as bf16x2 t2 (102.4 MB)
  void* tbuf = carve((size_t)R * N * 64 * sizeof(unsigned));
  unsigned short* t1b = (unsigned short*)tbuf;
  unsigned* t2p = (unsigned*)tbuf;
  unsigned short* xb = (unsigned short*)carve((size_t)N * 128 * 2);
  unsigned short* hb = (unsigned short*)carve((size_t)N * 64 * 2);
  unsigned short* W1t = (unsigned short*)carve((size_t)R * 64 * 128 * 2);
  unsigned short* Wmut = (unsigned short*)carve((size_t)R * 64 * 64 * 2);
  unsigned short* Wlvt = (unsigned short*)carve((size_t)R * 64 * 64 * 2);
  float* aq2 = (float*)carve((size_t)2 * R * N * sizeof(float));
  float* ak2 = (float*)carve((size_t)2 * R * N * sizeof(float));
  unsigned* maxk_enc = (unsigned*)carve(2 * R * sizeof(unsigned));
  int* deg = (int*)carve((size_t)N * sizeof(int));
  int* fill = (int*)carve((size_t)N * sizeof(int));
  int* row_ptr = (int*)carve((size_t)(N + 1) * sizeof(int));
  int* bsum = (int*)carve(256 * sizeof(int));
  int* edges = (int*)carve((size_t)E * sizeof(int));

  const int* e_src = edge_index;
  const int* e_dst = edge_index + E;

  // ---- prep: bf16 conversions + weight transposes ----
  cvt_bf16_kernel<<<(N * 128 / 4 + 255) / 256, 256, 0, stream>>>(x, xb,
                                                                 N * 128);
  transpose_w_kernel<<<3 * R, 256, 0, stream>>>(W1, Wmu, Wlv, W1t, Wmut, Wlvt);

  // ---- CSR build ----
  hipMemsetAsync(deg, 0, (size_t)N * sizeof(int), stream);
  hipMemsetAsync(fill, 0, (size_t)N * sizeof(int), stream);
  hipMemsetAsync(maxk_enc, 0, 2 * R * sizeof(unsigned), stream);
  count_deg_kernel<<<(E + 255) / 256, 256, 0, stream>>>(e_dst, deg, E);
  const int nchunk = (N + SCHUNK - 1) / SCHUNK;
  scan_p1<<<nchunk, 256, 0, stream>>>(deg, bsum, N);
  scan_p2<<<1, 64, 0, stream>>>(bsum, nchunk);
  scan_p3<<<nchunk, 256, 0, stream>>>(deg, bsum, row_ptr, N);
  scatter_kernel<<<(E + 255) / 256, 256, 0, stream>>>(e_src, e_dst, edge_type,
                                                      row_ptr, fill, edges, E);

  const int nb64 = (N + 63) / 64;
  const int agg_blocks = (N + 3) / 4;

  // ---- layer 1: IN=128 -> H=64 (MFMA, bf16 t) ----
  transform1_mfma<<<dim3(R, nb64), 256, 0, stream>>>(xb, W1t, q1, k1, t1b,
                                                     aq2, ak2, N);
  rowmax_kernel<<<dim3(R, 32), 256, 0, stream>>>(ak2, maxk_enc, N);
  aggregate_kernel<<<agg_blocks, 256, 0, stream>>>(
      row_ptr, edges, t1b, aq2, ak2, maxk_enc, b1, hb, N);

  // re-zero maxk for the 16 rows of layer 2
  hipMemsetAsync(maxk_enc, 0, 2 * R * sizeof(unsigned), stream);

  // ---- fused conv_mu + conv_logvar (MFMA, bf16x2 t2) + output linears ----
  transform2_mfma<<<dim3(R, nb64), 256, 0, stream>>>(
      hb, Wmut, Wlvt, qmu, kmu, qlv, klv, t2p, aq2, ak2, N);
  rowmax_kernel<<<dim3(2 * R, 32), 256, 0, stream>>>(ak2, maxk_enc, N);
  aggregate2_kernel<<<agg_blocks, 256, 0, stream>>>(
      row_ptr, edges, t2p, aq2, ak2, maxk_enc, bmu, blv, Wm, bm, Wl, bl,
      out_mu, out_ls, N);
}

// Round 13
// 563.003 us; speedup vs baseline: 1.2258x; 1.0963x over previous
//
#include <hip/hip_runtime.h>
#include <cstdint>

// N=50000 nodes, E=1.6M edges, IN=128, H=64, OUT=32, R=8
#define HDIM 64
#define ODIM 32
#define NEG_SLOPE 0.2f
#define SCHUNK 2048
#define EPB 8192  // edges per block in bucket_pass1

typedef __attribute__((ext_vector_type(8))) short v8s;   // 8 bf16 (4 VGPRs)
typedef __attribute__((ext_vector_type(4))) float v4f;   // MFMA accumulator

__device__ __forceinline__ unsigned f2bf_rne(float f) {
  unsigned u = __float_as_uint(f);
  return (u + 0x7FFFu + ((u >> 16) & 1u)) >> 16;  // round-to-nearest-even
}

// monotonic float<->uint order-preserving encode (for atomicMax on floats)
__device__ __forceinline__ unsigned fenc(float f) {
  unsigned u = __float_as_uint(f);
  return (u & 0x80000000u) ? ~u : (u | 0x80000000u);
}
__device__ __forceinline__ float fdec(unsigned e) {
  unsigned u = (e & 0x80000000u) ? (e ^ 0x80000000u) : ~e;
  return __uint_as_float(u);
}

// ---------------------------------------------------------------------------
// Prep: fp32 -> bf16 convert (x), weight transpose+convert -> [r][o][k] bf16.
// ---------------------------------------------------------------------------
__global__ __launch_bounds__(256) void cvt_bf16_kernel(
    const float* __restrict__ in, unsigned short* __restrict__ out, int n) {
  int i = (blockIdx.x * 256 + threadIdx.x) * 4;
  if (i + 3 < n) {
    float4 v = *(const float4*)&in[i];
    ushort4 o;
    o.x = (unsigned short)f2bf_rne(v.x);
    o.y = (unsigned short)f2bf_rne(v.y);
    o.z = (unsigned short)f2bf_rne(v.z);
    o.w = (unsigned short)f2bf_rne(v.w);
    *(ushort4*)&out[i] = o;
  }
}

__global__ __launch_bounds__(256) void transpose_w_kernel(
    const float* __restrict__ W1, const float* __restrict__ Wmu,
    const float* __restrict__ Wlv, unsigned short* __restrict__ W1t,
    unsigned short* __restrict__ Wmut, unsigned short* __restrict__ Wlvt) {
  const int b = blockIdx.x;  // 0..23
  const int r = b & 7;
  const int which = b >> 3;
  const float* src;
  unsigned short* dst;
  int K;
  if (which == 0) {
    src = W1; dst = W1t; K = 128;
  } else if (which == 1) {
    src = Wmu; dst = Wmut; K = 64;
  } else {
    src = Wlv; dst = Wlvt; K = 64;
  }
  for (int idx = threadIdx.x; idx < K * 64; idx += 256) {
    const int kk = idx >> 6, o = idx & 63;
    dst[((size_t)r * 64 + o) * K + kk] =
        (unsigned short)f2bf_rne(src[((size_t)r * K + kk) * 64 + o]);
  }
}

// ---------------------------------------------------------------------------
// CSR build: degree count + 3-phase scan (unchanged)
// ---------------------------------------------------------------------------
__global__ __launch_bounds__(256) void count_deg_kernel(
    const int* __restrict__ dst, int* __restrict__ deg, int E) {
  int e = blockIdx.x * 256 + threadIdx.x;
  if (e < E) atomicAdd(&deg[dst[e]], 1);
}

__global__ __launch_bounds__(256) void scan_p1(const int* __restrict__ deg,
                                               int* __restrict__ bsum, int n) {
  int base = blockIdx.x * SCHUNK + threadIdx.x * 8;
  int s = 0;
#pragma unroll
  for (int j = 0; j < 8; j++) {
    int i = base + j;
    if (i < n) s += deg[i];
  }
#pragma unroll
  for (int d = 1; d < 64; d <<= 1) s += __shfl_xor(s, d, 64);
  __shared__ int ws[4];
  if ((threadIdx.x & 63) == 0) ws[threadIdx.x >> 6] = s;
  __syncthreads();
  if (threadIdx.x == 0) bsum[blockIdx.x] = ws[0] + ws[1] + ws[2] + ws[3];
}

__global__ void scan_p2(int* bsum, int nb) {
  int i = threadIdx.x;
  int v = (i < nb) ? bsum[i] : 0;
  int orig = v;
#pragma unroll
  for (int d = 1; d < 64; d <<= 1) {
    int up = __shfl_up(v, d, 64);
    if (i >= d) v += up;
  }
  if (i < nb) bsum[i] = v - orig;
}

__global__ __launch_bounds__(256) void scan_p3(const int* __restrict__ deg,
                                               const int* __restrict__ bsum,
                                               int* __restrict__ row_ptr,
                                               int n) {
  int base = blockIdx.x * SCHUNK + threadIdx.x * 8;
  int vals[8];
  int s = 0;
#pragma unroll
  for (int j = 0; j < 8; j++) {
    int i = base + j;
    vals[j] = (i < n) ? deg[i] : 0;
    s += vals[j];
  }
  int lane = threadIdx.x & 63, w = threadIdx.x >> 6;
  int v = s;
#pragma unroll
  for (int d = 1; d < 64; d <<= 1) {
    int up = __shfl_up(v, d, 64);
    if (lane >= d) v += up;
  }
  __shared__ int wsum[4];
  if (lane == 63) wsum[w] = v;
  __syncthreads();
  int woff = 0;
#pragma unroll
  for (int i = 0; i < 4; i++) woff += (i < w) ? wsum[i] : 0;
  int off = bsum[blockIdx.x] + woff + v - s;
#pragma unroll
  for (int j = 0; j < 8; j++) {
    int i = base + j;
    off += vals[j];
    if (i < n) row_ptr[i + 1] = off;
  }
  if (blockIdx.x == 0 && threadIdx.x == 0) row_ptr[0] = 0;
}

// ---------------------------------------------------------------------------
// Bucketed edge placement (replaces the old atomic scatter; fixes the 16x
// write amplification from cross-XCD 4B scattered writes).
// Bucket = 256 consecutive dst rows; bucket regions align with CSR order.
// ---------------------------------------------------------------------------
__global__ __launch_bounds__(256) void bucket_cursor_init(
    const int* __restrict__ row_ptr, int* __restrict__ cursor, int N, int nb) {
  int i = threadIdx.x;
  if (i < nb) cursor[i] = row_ptr[min(i * 256, N)];
}

// pass 1: group edges by bucket via LDS staging; one global atomic per
// (block,bin); coalesced run flush. rec = dstlow8<<19 | etype<<16 | src16.
__global__ __launch_bounds__(256) void bucket_pass1(
    const int* __restrict__ src, const int* __restrict__ dst,
    const int* __restrict__ etype, int* __restrict__ cursor,
    unsigned* __restrict__ tmp, int E) {
  __shared__ int hist[256];
  __shared__ int binstart[256];
  __shared__ int gbase[256];
  __shared__ int fill[256];
  __shared__ int wsum[4];
  __shared__ unsigned stage[EPB];
  __shared__ unsigned char binof[EPB];
  const int tid = threadIdx.x;
  const int e0 = blockIdx.x * EPB;
  const int cnt = min(EPB, E - e0);

  hist[tid] = 0;
  fill[tid] = 0;
  __syncthreads();
  for (int j = tid; j < cnt; j += 256) atomicAdd(&hist[dst[e0 + j] >> 8], 1);
  __syncthreads();

  // exclusive scan of hist (256 entries) + reserve global runs
  const int hv = hist[tid];
  {
    const int lane = tid & 63, w = tid >> 6;
    int iv = hv;
#pragma unroll
    for (int d = 1; d < 64; d <<= 1) {
      int up = __shfl_up(iv, d, 64);
      if (lane >= d) iv += up;
    }
    if (lane == 63) wsum[w] = iv;
    __syncthreads();
    int woff = 0;
#pragma unroll
    for (int i = 0; i < 4; i++) woff += (i < w) ? wsum[i] : 0;
    binstart[tid] = woff + iv - hv;  // exclusive prefix
    if (hv > 0) gbase[tid] = atomicAdd(&cursor[tid], hv);
  }
  __syncthreads();

  // place records into LDS staging grouped by bin
  for (int j = tid; j < cnt; j += 256) {
    const int d = dst[e0 + j];
    const int b = d >> 8;
    const unsigned rec = ((unsigned)(d & 255) << 19) |
                         ((unsigned)etype[e0 + j] << 16) |
                         (unsigned)src[e0 + j];
    const int slot = binstart[b] + atomicAdd(&fill[b], 1);
    stage[slot] = rec;
    binof[slot] = (unsigned char)b;
  }
  __syncthreads();

  // coalesced flush: consecutive slots -> consecutive global addresses
  for (int s = tid; s < cnt; s += 256) {
    const int b = binof[s];
    tmp[gbase[b] + (s - binstart[b])] = stage[s];
  }
}

// pass 2: one block per bucket; LDS fill counters; scattered writes stay
// inside the block-owned contiguous region (single-XCD line ownership).
__global__ __launch_bounds__(256) void bucket_pass2(
    const int* __restrict__ row_ptr, const unsigned* __restrict__ tmp,
    int* __restrict__ edges, int N) {
  __shared__ int rp[257];
  __shared__ int fill[256];
  const int tid = threadIdx.x;
  const int rowbase = blockIdx.x * 256;
  const int rowcnt = min(256, N - rowbase);
  for (int i = tid; i <= rowcnt; i += 256) rp[i] = row_ptr[rowbase + i];
  fill[tid] = 0;
  __syncthreads();
  const int beg = rp[0];
  const int endv = rp[rowcnt];
  for (int i = beg + tid; i < endv; i += 256) {
    const unsigned rec = tmp[i];
    const int dlow = rec >> 19;
    const int pos = rp[dlow] + atomicAdd(&fill[dlow], 1);
    edges[pos] = (int)(rec & 0x7FFFFu);  // src | etype<<16
  }
}

// ---------------------------------------------------------------------------
// Parallel row max: grid (rows, 32 chunks); one atomicMax(enc) per block.
// ---------------------------------------------------------------------------
__global__ __launch_bounds__(256) void rowmax_kernel(
    const float* __restrict__ ak, unsigned* __restrict__ maxk_enc, int N) {
  const int row = blockIdx.x;
  const int nchunks = gridDim.y;
  const int per = (N + nchunks - 1) / nchunks;
  const int beg = blockIdx.y * per;
  const int end = min(N, beg + per);
  const float* r = ak + (size_t)row * N;
  float m = -1e30f;
  for (int i = beg + threadIdx.x; i < end; i += 256) m = fmaxf(m, r[i]);
#pragma unroll
  for (int d = 1; d < 64; d <<= 1) m = fmaxf(m, __shfl_xor(m, d, 64));
  __shared__ float ws[4];
  if ((threadIdx.x & 63) == 0) ws[threadIdx.x >> 6] = m;
  __syncthreads();
  if (threadIdx.x == 0) {
    float bm = fmaxf(fmaxf(ws[0], ws[1]), fmaxf(ws[2], ws[3]));
    atomicMax(&maxk_enc[row], fenc(bm));
  }
}

// ---------------------------------------------------------------------------
// Layer-1 transform via MFMA bf16: t[r] = x @ W1[r], + fp32 aq/ak epilogue.
// ---------------------------------------------------------------------------
__global__ __launch_bounds__(256) void transform1_mfma(
    const unsigned short* __restrict__ xb,
    const unsigned short* __restrict__ W1t, const float* __restrict__ q,
    const float* __restrict__ k, unsigned short* __restrict__ tb,
    float* __restrict__ aq, float* __restrict__ ak, int N) {
  __shared__ unsigned short st[4][16][72];
  const int r = blockIdx.x;
  const int tid = threadIdx.x;
  const int w = tid >> 6;
  const int lane = tid & 63;
  const int quad = lane >> 4;
  const int mrow = lane & 15;
  const int n0w = blockIdx.y * 64 + w * 16;

  const int gA = min(n0w + mrow, N - 1);
  const unsigned short* arow = xb + (size_t)gA * 128 + quad * 8;
  const unsigned short* wrow = W1t + ((size_t)r * 64 + mrow) * 128 + quad * 8;

  v4f acc[4];
#pragma unroll
  for (int tt = 0; tt < 4; tt++) acc[tt] = (v4f){0.f, 0.f, 0.f, 0.f};

#pragma unroll
  for (int k0 = 0; k0 < 128; k0 += 32) {
    v8s a = *(const v8s*)(arow + k0);
#pragma unroll
    for (int tt = 0; tt < 4; tt++) {
      v8s b = *(const v8s*)(wrow + (size_t)tt * 16 * 128 + k0);
      acc[tt] = __builtin_amdgcn_mfma_f32_16x16x32_bf16(a, b, acc[tt], 0, 0, 0);
    }
  }

  float qv[4], kv[4];
#pragma unroll
  for (int tt = 0; tt < 4; tt++) {
    qv[tt] = q[tt * 16 + mrow];
    kv[tt] = k[tt * 16 + mrow];
  }

#pragma unroll
  for (int i = 0; i < 4; i++) {
    float vq = 0.f, vk = 0.f;
#pragma unroll
    for (int tt = 0; tt < 4; tt++) {
      vq = fmaf(acc[tt][i], qv[tt], vq);
      vk = fmaf(acc[tt][i], kv[tt], vk);
      st[w][quad * 4 + i][tt * 16 + mrow] =
          (unsigned short)f2bf_rne(acc[tt][i]);
    }
#pragma unroll
    for (int d = 1; d < 16; d <<= 1) {
      vq += __shfl_xor(vq, d, 64);
      vk += __shfl_xor(vk, d, 64);
    }
    const int gn = n0w + quad * 4 + i;
    if (mrow == 0 && gn < N) {
      aq[(size_t)r * N + gn] = vq;
      ak[(size_t)r * N + gn] = vk;
    }
  }
  __syncthreads();

  const int row = lane >> 2, cg = lane & 3;
  const int gns = n0w + row;
  if (gns < N) {
    const uint4 v0 = *(const uint4*)&st[w][row][cg * 16];
    const uint4 v1 = *(const uint4*)&st[w][row][cg * 16 + 8];
    uint4* dst = (uint4*)&tb[((size_t)r * N + gns) * 64 + cg * 16];
    dst[0] = v0;
    dst[1] = v1;
  }
}

// ---------------------------------------------------------------------------
// Fused mu+lv transform via MFMA bf16 (CIN=64).
// ---------------------------------------------------------------------------
__global__ __launch_bounds__(256) void transform2_mfma(
    const unsigned short* __restrict__ hb,
    const unsigned short* __restrict__ Wmut,
    const unsigned short* __restrict__ Wlvt, const float* __restrict__ qa,
    const float* __restrict__ ka, const float* __restrict__ qb,
    const float* __restrict__ kb, unsigned* __restrict__ t2p,
    float* __restrict__ aq2, float* __restrict__ ak2, int N) {
  __shared__ unsigned st2[4][16][68];
  const int r = blockIdx.x;
  const int tid = threadIdx.x;
  const int w = tid >> 6;
  const int lane = tid & 63;
  const int quad = lane >> 4;
  const int mrow = lane & 15;
  const int n0w = blockIdx.y * 64 + w * 16;

  const int gA = min(n0w + mrow, N - 1);
  const unsigned short* arow = hb + (size_t)gA * 64 + quad * 8;
  const size_t woff = ((size_t)r * 64 + mrow) * 64 + quad * 8;

  v4f am[4], al[4];
#pragma unroll
  for (int tt = 0; tt < 4; tt++) {
    am[tt] = (v4f){0.f, 0.f, 0.f, 0.f};
    al[tt] = (v4f){0.f, 0.f, 0.f, 0.f};
  }

#pragma unroll
  for (int k0 = 0; k0 < 64; k0 += 32) {
    v8s a = *(const v8s*)(arow + k0);
#pragma unroll
    for (int tt = 0; tt < 4; tt++) {
      v8s bm = *(const v8s*)(Wmut + woff + (size_t)tt * 16 * 64 + k0);
      v8s bl = *(const v8s*)(Wlvt + woff + (size_t)tt * 16 * 64 + k0);
      am[tt] = __builtin_amdgcn_mfma_f32_16x16x32_bf16(a, bm, am[tt], 0, 0, 0);
      al[tt] = __builtin_amdgcn_mfma_f32_16x16x32_bf16(a, bl, al[tt], 0, 0, 0);
    }
  }

  float qmv[4], kmv[4], qlv2[4], klv2[4];
#pragma unroll
  for (int tt = 0; tt < 4; tt++) {
    qmv[tt] = qa[tt * 16 + mrow];
    kmv[tt] = ka[tt * 16 + mrow];
    qlv2[tt] = qb[tt * 16 + mrow];
    klv2[tt] = kb[tt * 16 + mrow];
  }

#pragma unroll
  for (int i = 0; i < 4; i++) {
    float vqm = 0.f, vkm = 0.f, vql = 0.f, vkl = 0.f;
#pragma unroll
    for (int tt = 0; tt < 4; tt++) {
      vqm = fmaf(am[tt][i], qmv[tt], vqm);
      vkm = fmaf(am[tt][i], kmv[tt], vkm);
      vql = fmaf(al[tt][i], qlv2[tt], vql);
      vkl = fmaf(al[tt][i], klv2[tt], vkl);
      st2[w][quad * 4 + i][tt * 16 + mrow] =
          f2bf_rne(am[tt][i]) | (f2bf_rne(al[tt][i]) << 16);
    }
#pragma unroll
    for (int d = 1; d < 16; d <<= 1) {
      vqm += __shfl_xor(vqm, d, 64);
      vkm += __shfl_xor(vkm, d, 64);
      vql += __shfl_xor(vql, d, 64);
      vkl += __shfl_xor(vkl, d, 64);
    }
    const int gn = n0w + quad * 4 + i;
    if (mrow == 0 && gn < N) {
      aq2[(size_t)r * N + gn] = vqm;
      ak2[(size_t)r * N + gn] = vkm;
      aq2[(size_t)(8 + r) * N + gn] = vql;
      ak2[(size_t)(8 + r) * N + gn] = vkl;
    }
  }
  __syncthreads();

  const int row = lane >> 2, cg = lane & 3;
  const int gns = n0w + row;
  if (gns < N) {
    unsigned* dst = &t2p[((size_t)r * N + gns) * 64 + cg * 16];
#pragma unroll
    for (int s = 0; s < 4; s++)
      *(uint4*)(dst + s * 4) = *(const uint4*)&st2[w][row][cg * 16 + s * 4];
  }
}

// ---------------------------------------------------------------------------
// Layer-1 aggregate: single-pass softmax (upper-bound shift), bf16 t gather.
// ---------------------------------------------------------------------------
__global__ __launch_bounds__(256) void aggregate_kernel(
    const int* __restrict__ row_ptr, const int* __restrict__ edges,
    const unsigned short* __restrict__ tb, const float* __restrict__ aq,
    const float* __restrict__ ak, const unsigned* __restrict__ maxk_enc,
    const float* __restrict__ bias, unsigned short* __restrict__ hb, int N) {
  const int tid = threadIdx.x;
  const int w = tid >> 6, o = tid & 63;
  int wid = blockIdx.x * 4 + w;
  const bool valid = wid < N;
  if (!valid) wid = N - 1;
  const int beg = row_ptr[wid];
  const int end = valid ? row_ptr[wid + 1] : beg;
  const int deg = end - beg;

  const float aqw = aq[(size_t)(o & 7) * N + wid];

  float v = aqw + fdec(maxk_enc[o & 7]);
  v = (v >= 0.f) ? v : NEG_SLOPE * v;
#pragma unroll
  for (int d = 1; d < 8; d <<= 1) v = fmaxf(v, __shfl_xor(v, d, 64));
  const float m = __shfl(v, 0, 64);

  float s = 0.f, acc = 0.f;
  for (int base = 0; base < deg; base += 64) {
    const int j = base + o;
    const int gcount = min(64, deg - base);
    const int packed = edges[beg + min(j, deg - 1)];
    const int src = packed & 0xFFFF;
    const int rr = packed >> 16;
    const int idx = rr * N + src;
    float x = __shfl(aqw, rr, 64) + ak[idx];
    x = (x >= 0.f) ? x : NEG_SLOPE * x;
    const float p = (j < deg) ? __expf(x - m) : 0.f;
    s += p;
    const int g8 = (gcount + 7) & ~7;
    for (int u = 0; u < g8; u += 8) {
      float pu[8];
      int iu[8];
#pragma unroll
      for (int q = 0; q < 8; q++) {
        pu[q] = __shfl(p, u + q, 64);
        iu[q] = __shfl(idx, u + q, 64);
      }
      unsigned short tv[8];
#pragma unroll
      for (int q = 0; q < 8; q++) tv[q] = tb[(size_t)iu[q] * 64 + o];
#pragma unroll
      for (int q = 0; q < 8; q++)
        acc = fmaf(pu[q], __uint_as_float((unsigned)tv[q] << 16), acc);
    }
  }
#pragma unroll
  for (int d = 1; d < 64; d <<= 1) s += __shfl_xor(s, d, 64);

  if (valid) {
    const float res = acc / (s + 1e-16f) + bias[o];
    hb[(size_t)wid * 64 + o] = (unsigned short)f2bf_rne(fmaxf(res, 0.f));
  }
}

// ---------------------------------------------------------------------------
// Fused mu+lv aggregate: single-pass, bf16x2 t2, unroll-8 gather, + linears.
// ---------------------------------------------------------------------------
__global__ __launch_bounds__(256) void aggregate2_kernel(
    const int* __restrict__ row_ptr, const int* __restrict__ edges,
    const unsigned* __restrict__ t2p, const float* __restrict__ aq2,
    const float* __restrict__ ak2, const unsigned* __restrict__ maxk2_enc,
    const float* __restrict__ bmu, const float* __restrict__ blv,
    const float* __restrict__ Wm, const float* __restrict__ bm,
    const float* __restrict__ Wlin, const float* __restrict__ bl,
    float* __restrict__ out_mu, float* __restrict__ out_ls, int N) {
  __shared__ float WmL[2048];
  __shared__ float WlL[2048];
  __shared__ float bL[64];
  __shared__ float hL[4][130];
  const int tid = threadIdx.x;
  for (int i = tid; i < 2048; i += 256) {
    WmL[i] = Wm[i];
    WlL[i] = Wlin[i];
  }
  if (tid < 32) {
    bL[tid] = bm[tid];
    bL[32 + tid] = bl[tid];
  }
  __syncthreads();

  const int w = tid >> 6, o = tid & 63;
  int wid = blockIdx.x * 4 + w;
  const bool valid = wid < N;
  if (!valid) wid = N - 1;
  const int beg = row_ptr[wid];
  const int end = valid ? row_ptr[wid + 1] : beg;
  const int deg = end - beg;

  const float aqw = aq2[(size_t)(o & 15) * N + wid];

  float v = aqw + fdec(maxk2_enc[o & 15]);
  v = (v >= 0.f) ? v : NEG_SLOPE * v;
#pragma unroll
  for (int d = 1; d < 8; d <<= 1) v = fmaxf(v, __shfl_xor(v, d, 64));
  const float m0 = __shfl(v, 0, 64);
  const float m1 = __shfl(v, 8, 64);

  float s0 = 0.f, s1 = 0.f, acc0 = 0.f, acc1 = 0.f;
  for (int base = 0; base < deg; base += 64) {
    const int j = base + o;
    const int gcount = min(64, deg - base);
    const int packed = edges[beg + min(j, deg - 1)];
    const int src = packed & 0xFFFF;
    const int rr = packed >> 16;
    const int idx = rr * N + src;
    float x0 = __shfl(aqw, rr, 64) + ak2[idx];
    float x1 = __shfl(aqw, 8 + rr, 64) + ak2[idx + 8 * N];
    x0 = (x0 >= 0.f) ? x0 : NEG_SLOPE * x0;
    x1 = (x1 >= 0.f) ? x1 : NEG_SLOPE * x1;
    const float p0 = (j < deg) ? __expf(x0 - m0) : 0.f;
    const float p1 = (j < deg) ? __expf(x1 - m1) : 0.f;
    s0 += p0;
    s1 += p1;
    const int g8 = (gcount + 7) & ~7;
    for (int u = 0; u < g8; u += 8) {
      float pu0[8], pu1[8];
      int iu[8];
#pragma unroll
      for (int q = 0; q < 8; q++) {
        pu0[q] = __shfl(p0, u + q, 64);
        pu1[q] = __shfl(p1, u + q, 64);
        iu[q] = __shfl(idx, u + q, 64);
      }
      unsigned pk[8];
#pragma unroll
      for (int q = 0; q < 8; q++) pk[q] = t2p[(size_t)iu[q] * 64 + o];
#pragma unroll
      for (int q = 0; q < 8; q++) {
        acc0 = fmaf(pu0[q], __uint_as_float(pk[q] << 16), acc0);
        acc1 = fmaf(pu1[q], __uint_as_float(pk[q] & 0xFFFF0000u), acc1);
      }
    }
  }
#pragma unroll
  for (int d = 1; d < 64; d <<= 1) {
    s0 += __shfl_xor(s0, d, 64);
    s1 += __shfl_xor(s1, d, 64);
  }

  const float h0 = fmaxf(acc0 / (s0 + 1e-16f) + bmu[o], 0.f);
  const float h1 = fmaxf(acc1 / (s1 + 1e-16f) + blv[o], 0.f);
  hL[w][o] = h0;
  hL[w][64 + o] = h1;
  __syncthreads();

  const float* hrow = &hL[w][(o >= 32) ? 64 : 0];
  const float* WL = (o >= 32) ? WlL : WmL;
  const int j = o & 31;
  float acc = 0.f;
#pragma unroll 8
  for (int c = 0; c < 64; c++) acc = fmaf(hrow[c], WL[c * 32 + j], acc);
  if (valid) {
    if (o < 32)
      out_mu[(size_t)wid * 32 + j] = acc + bL[j];
    else
      out_ls[(size_t)wid * 32 + j] = (acc + bL[32 + j]) * 0.5f;
  }
}

// ---------------------------------------------------------------------------
extern "C" void kernel_launch(void* const* d_in, const int* in_sizes, int n_in,
                              void* d_out, int out_size, void* d_ws,
                              size_t ws_size, hipStream_t stream) {
  const float* x = (const float*)d_in[0];
  const int* edge_index = (const int*)d_in[1];
  const int* edge_type = (const int*)d_in[2];
  const float* W1 = (const float*)d_in[3];
  const float* q1 = (const float*)d_in[4];
  const float* k1 = (const float*)d_in[5];
  const float* b1 = (const float*)d_in[6];
  const float* Wmu = (const float*)d_in[7];
  const float* qmu = (const float*)d_in[8];
  const float* kmu = (const float*)d_in[9];
  const float* bmu = (const float*)d_in[10];
  const float* Wlv = (const float*)d_in[11];
  const float* qlv = (const float*)d_in[12];
  const float* klv = (const float*)d_in[13];
  const float* blv = (const float*)d_in[14];
  const float* Wm = (const float*)d_in[15];
  const float* bm = (const float*)d_in[16];
  const float* Wl = (const float*)d_in[17];
  const float* bl = (const float*)d_in[18];

  const int N = in_sizes[0] / 128;         // 50000
  const int E = in_sizes[2];               // 1.6M
  const int R = in_sizes[3] / (128 * 64);  // 8

  float* out_mu = (float*)d_out;
  float* out_ls = (float*)d_out + (size_t)N * ODIM;

  char* wsp = (char*)d_ws;
  size_t off = 0;
  auto carve = [&](size_t bytes) {
    void* p = wsp + off;
    off += (bytes + 255) & ~(size_t)255;
    return p;
  };

  // t buffer: layer-1 bf16 (51.2 MB) then reused as bf16x2 t2 (102.4 MB)
  void* tbuf = carve((size_t)R * N * 64 * sizeof(unsigned));
  unsigned short* t1b = (unsigned short*)tbuf;
  unsigned* t2p = (unsigned*)tbuf;
  unsigned short* xb = (unsigned short*)carve((size_t)N * 128 * 2);
  unsigned short* hb = (unsigned short*)carve((size_t)N * 64 * 2);
  unsigned short* W1t = (unsigned short*)carve((size_t)R * 64 * 128 * 2);
  unsigned short* Wmut = (unsigned short*)carve((size_t)R * 64 * 64 * 2);
  unsigned short* Wlvt = (unsigned short*)carve((size_t)R * 64 * 64 * 2);
  float* aq2 = (float*)carve((size_t)2 * R * N * sizeof(float));
  float* ak2 = (float*)carve((size_t)2 * R * N * sizeof(float));
  unsigned* maxk_enc = (unsigned*)carve(2 * R * sizeof(unsigned));
  int* deg = (int*)carve((size_t)N * sizeof(int));
  int* row_ptr = (int*)carve((size_t)(N + 1) * sizeof(int));
  int* bsum = (int*)carve(256 * sizeof(int));
  int* cursor = (int*)carve(256 * sizeof(int));
  unsigned* tmp = (unsigned*)carve((size_t)E * sizeof(unsigned));
  int* edges = (int*)carve((size_t)E * sizeof(int));

  const int* e_src = edge_index;
  const int* e_dst = edge_index + E;

  // ---- prep: bf16 conversions + weight transposes ----
  cvt_bf16_kernel<<<(N * 128 / 4 + 255) / 256, 256, 0, stream>>>(x, xb,
                                                                 N * 128);
  transpose_w_kernel<<<3 * R, 256, 0, stream>>>(W1, Wmu, Wlv, W1t, Wmut, Wlvt);

  // ---- CSR build ----
  hipMemsetAsync(deg, 0, (size_t)N * sizeof(int), stream);
  hipMemsetAsync(maxk_enc, 0, 2 * R * sizeof(unsigned), stream);
  count_deg_kernel<<<(E + 255) / 256, 256, 0, stream>>>(e_dst, deg, E);
  const int nchunk = (N + SCHUNK - 1) / SCHUNK;
  scan_p1<<<nchunk, 256, 0, stream>>>(deg, bsum, N);
  scan_p2<<<1, 64, 0, stream>>>(bsum, nchunk);
  scan_p3<<<nchunk, 256, 0, stream>>>(deg, bsum, row_ptr, N);

  // ---- bucketed edge placement (2-pass, no cross-XCD line sharing) ----
  const int nbuck = (N + 255) >> 8;  // 196 <= 256
  bucket_cursor_init<<<1, 256, 0, stream>>>(row_ptr, cursor, N, nbuck);
  bucket_pass1<<<(E + EPB - 1) / EPB, 256, 0, stream>>>(e_src, e_dst,
                                                        edge_type, cursor,
                                                        tmp, E);
  bucket_pass2<<<nbuck, 256, 0, stream>>>(row_ptr, tmp, edges, N);

  const int nb64 = (N + 63) / 64;
  const int agg_blocks = (N + 3) / 4;

  // ---- layer 1: IN=128 -> H=64 (MFMA, bf16 t) ----
  transform1_mfma<<<dim3(R, nb64), 256, 0, stream>>>(xb, W1t, q1, k1, t1b,
                                                     aq2, ak2, N);
  rowmax_kernel<<<dim3(R, 32), 256, 0, stream>>>(ak2, maxk_enc, N);
  aggregate_kernel<<<agg_blocks, 256, 0, stream>>>(
      row_ptr, edges, t1b, aq2, ak2, maxk_enc, b1, hb, N);

  // re-zero maxk for the 16 rows of layer 2
  hipMemsetAsync(maxk_enc, 0, 2 * R * sizeof(unsigned), stream);

  // ---- fused conv_mu + conv_logvar (MFMA, bf16x2 t2) + output linears ----
  transform2_mfma<<<dim3(R, nb64), 256, 0, stream>>>(
      hb, Wmut, Wlvt, qmu, kmu, qlv, klv, t2p, aq2, ak2, N);
  rowmax_kernel<<<dim3(2 * R, 32), 256, 0, stream>>>(ak2, maxk_enc, N);
  aggregate2_kernel<<<agg_blocks, 256, 0, stream>>>(
      row_ptr, edges, t2p, aq2, ak2, maxk_enc, bmu, blv, Wm, bm, Wl, bl,
      out_mu, out_ls, N);
}